// Round 2
// baseline (1525.000 us; speedup 1.0000x reference)
//
#include <hip/hip_runtime.h>
#include <math.h>

#define C_CH 512
#define L_SEQ 1024
#define DK 64
#define NP 4

// ---------------------------------------------------------------------------
// Kernel 1: transpose conv weights W[co][ci][t] -> Wt[t_global][ci][co]
// t_global = toff[plane] + t, toff = {0,1,4,9}, 16 slices of 512x512 total.
// ---------------------------------------------------------------------------
__global__ __launch_bounds__(256)
void transpose_w_kernel(const float* __restrict__ w0, const float* __restrict__ w1,
                        const float* __restrict__ w2, const float* __restrict__ w3,
                        float* __restrict__ Wt) {
    int z = blockIdx.z;
    int plane, t;
    if (z < 1)      { plane = 0; t = z; }
    else if (z < 4) { plane = 1; t = z - 1; }
    else if (z < 9) { plane = 2; t = z - 4; }
    else            { plane = 3; t = z - 9; }
    const float* W = (plane == 0) ? w0 : (plane == 1) ? w1 : (plane == 2) ? w2 : w3;
    const int f = (plane == 0) ? 1 : (plane == 1) ? 3 : (plane == 2) ? 5 : 7;

    int ci0 = blockIdx.x * 64;
    int co0 = blockIdx.y * 64;
    __shared__ float tile[64][65];
    int tid = threadIdx.x;
    int a  = tid & 63;   // fast index
    int bq = tid >> 6;   // 0..3

    // load: tile[ci_l][co_l] = W[co][ci][t]
    for (int rr = 0; rr < 16; rr++) {
        int co_l = bq + rr * 4;
        tile[a][co_l] = W[(size_t)(co0 + co_l) * (C_CH * f) + (size_t)(ci0 + a) * f + t];
    }
    __syncthreads();
    // store: Wt[z][ci][co], coalesced over co
    for (int rr = 0; rr < 16; rr++) {
        int ci_l = bq + rr * 4;
        Wt[((size_t)z * C_CH + (ci0 + ci_l)) * C_CH + co0 + a] = tile[ci_l][a];
    }
}

// ---------------------------------------------------------------------------
// Kernel 2: conv as GEMM.  y[b,co,pos] = bias[co] + sum_{t,ci} Wt[t][ci][co] *
// x[b,ci,pos+t-pad].  x is the raw Q/K buffer viewed as (B, 512, 1024).
// Output scattered into plane layout Out[(b*8+h)*NP+plane][l][d] with
// h = co>>6, l = (co&63)*16 + pos>>6, d = pos&63.
// Tile: 64 co x 128 pos, 256 threads, 4x8 outputs/thread.
// grid: (8 pos_tiles, 8 co_tiles, 16 = tensor*plane*b)
// ---------------------------------------------------------------------------
__global__ __launch_bounds__(256)
void conv_gemm_kernel(const float* __restrict__ Qin, const float* __restrict__ Kin,
                      const float* __restrict__ Wt,
                      const float* __restrict__ b0, const float* __restrict__ b1,
                      const float* __restrict__ b2, const float* __restrict__ b3,
                      float* __restrict__ Qp, float* __restrict__ Kp) {
    const int fs[4]   = {1, 3, 5, 7};
    const int toff[4] = {0, 1, 4, 9};
    int z      = blockIdx.z;
    int b      = z & 1;
    int plane  = (z >> 1) & 3;
    int tensor = z >> 3;
    const float* X    = (tensor ? Kin : Qin) + (size_t)b * C_CH * L_SEQ;
    const float* bias = (plane == 0) ? b0 : (plane == 1) ? b1 : (plane == 2) ? b2 : b3;
    float* Out = tensor ? Kp : Qp;
    const int f   = fs[plane];
    const int pad = (f - 1) >> 1;

    int pos0 = blockIdx.x * 128;
    int co0  = blockIdx.y * 64;

    __shared__ __align__(16) float Asm[32][64];
    __shared__ __align__(16) float Bsm[32][128];

    int tid = threadIdx.x;
    int tx = tid & 15;   // pos group
    int ty = tid >> 4;   // co group

    float acc[4][8];
    for (int i = 0; i < 4; i++)
        for (int j = 0; j < 8; j++) acc[i][j] = 0.f;

    for (int t = 0; t < f; t++) {
        const float* Wslice = Wt + (size_t)(toff[plane] + t) * C_CH * C_CH;
        int shift = t - pad;
        for (int cc = 0; cc < 16; cc++) {   // ci chunks of 32
            __syncthreads();
            {
                int colA = tid & 63, rowA = tid >> 6;       // 4 rows x 8 steps
                for (int r = 0; r < 8; r++) {
                    int rr = rowA * 8 + r;
                    Asm[rr][colA] = Wslice[(size_t)(cc * 32 + rr) * C_CH + co0 + colA];
                }
                int colB = tid & 127, rowB = tid >> 7;      // 2 rows x 16 steps
                int pg = pos0 + colB + shift;
                bool ok = (pg >= 0) && (pg < L_SEQ);
                for (int r = 0; r < 16; r++) {
                    int rr = rowB * 16 + r;
                    Bsm[rr][colB] = ok ? X[(size_t)(cc * 32 + rr) * L_SEQ + pg] : 0.f;
                }
            }
            __syncthreads();
#pragma unroll
            for (int kk = 0; kk < 32; kk++) {
                float4 a4  = *(const float4*)&Asm[kk][ty * 4];
                float4 bA  = *(const float4*)&Bsm[kk][tx * 4];
                float4 bB  = *(const float4*)&Bsm[kk][64 + tx * 4];
                float av[4] = {a4.x, a4.y, a4.z, a4.w};
                float bv[8] = {bA.x, bA.y, bA.z, bA.w, bB.x, bB.y, bB.z, bB.w};
                for (int i = 0; i < 4; i++)
                    for (int j = 0; j < 8; j++)
                        acc[i][j] = fmaf(av[i], bv[j], acc[i][j]);
            }
        }
    }

    // epilogue: scatter to plane layout
    int h = blockIdx.y;                       // co0>>6
    size_t pbase = ((size_t)(b * 8 + h) * NP + plane) * L_SEQ;
    for (int i = 0; i < 4; i++) {
        int c_local = ty * 4 + i;
        float bv = bias[co0 + c_local];
        int l0 = c_local * 16 + blockIdx.x * 2;   // pos0>>6 = blockIdx.x*2
        float4 v0 = make_float4(acc[i][0] + bv, acc[i][1] + bv, acc[i][2] + bv, acc[i][3] + bv);
        float4 v1 = make_float4(acc[i][4] + bv, acc[i][5] + bv, acc[i][6] + bv, acc[i][7] + bv);
        *(float4*)&Out[(pbase + l0) * DK + tx * 4]     = v0;
        *(float4*)&Out[(pbase + l0 + 1) * DK + tx * 4] = v1;
    }
}

// ---------------------------------------------------------------------------
// Kernel 3: per-(b2,h2,q) row.  The reference's cat(dim=0).reshape scrambles
// (plane,b,h): block index bb = b2*32 + h2*4 + p2 = plane*16 + b_orig*8 + h_orig.
// So for output (b2,h2):
//   plane  = b2*2 + (h2>>2)         (fixed across p2)
//   b_orig = (h2>>1) & 1            (fixed across p2)
//   h_orig = (h2&1)*4 + p2          (the "plane max" is a max over these heads)
// V / outputs use unscrambled (b2,h2).
// grid: (1024 q, 16 b2h2), 256 threads.
// ---------------------------------------------------------------------------
__global__ __launch_bounds__(256)
void attn_ctx_kernel(const float* __restrict__ Qp, const float* __restrict__ Kp,
                     const float* __restrict__ V,
                     float* __restrict__ out_ctx, float* __restrict__ out_attn) {
    int q   = blockIdx.x;
    int bh  = blockIdx.y;          // b2*8 + h2
    int tid = threadIdx.x;

    int b2 = bh >> 3, h2 = bh & 7;
    int plane  = b2 * 2 + (h2 >> 2);
    int b_orig = (h2 >> 1) & 1;
    int h_base = (h2 & 1) * 4;
    // slice index for "p2-th plane": (b_orig*8 + h_base + p2)*NP + plane
    size_t slice0 = ((size_t)(b_orig * 8 + h_base) * NP + plane);

    __shared__ __align__(16) float qv[NP * DK];
    __shared__ __align__(16) float sbuf[NP][L_SEQ];
    __shared__ __align__(16) float abuf[L_SEQ];
    __shared__ float red[4][NP];

    // load the 4 q-vectors (one per p2)
    {
        int p = tid >> 6, d = tid & 63;
        qv[tid] = Qp[((slice0 + (size_t)p * NP) * L_SEQ + q) * DK + d];
    }
    __syncthreads();

    int sub  = tid & 3;    // d-quarter
    int kloc = tid >> 2;   // 0..63
    float4 qreg[NP][4];
    for (int p = 0; p < NP; p++)
        for (int c = 0; c < 4; c++)
            qreg[p][c] = *(const float4*)&qv[p * DK + sub * 16 + c * 4];

    int nk    = q + 1;
    int npass = (nk + 63) >> 6;
    int kmax  = npass * 64;

    // Phase A: scores -> sbuf
    for (int pass = 0; pass < npass; pass++) {
        int k = pass * 64 + kloc;            // always < 1024, memory-safe
        float s[NP];
        for (int p = 0; p < NP; p++) {
            const float4* kr =
                (const float4*)(Kp + ((slice0 + (size_t)p * NP) * L_SEQ + k) * DK + sub * 16);
            float a = 0.f;
            for (int c = 0; c < 4; c++) {
                float4 kv = kr[c];
                float4 q4 = qreg[p][c];
                a += q4.x * kv.x + q4.y * kv.y + q4.z * kv.z + q4.w * kv.w;
            }
            s[p] = a;
        }
        for (int p = 0; p < NP; p++) {
            s[p] += __shfl_xor(s[p], 1);
            s[p] += __shfl_xor(s[p], 2);
        }
        if (sub == 0) {
            for (int p = 0; p < NP; p++)
                sbuf[p][k] = (k <= q) ? s[p] * 0.125f : -INFINITY;
        }
    }
    __syncthreads();

    int lane = tid & 63, wid = tid >> 6;

    // per-plane max
    float m[NP];
    for (int p = 0; p < NP; p++) m[p] = -INFINITY;
    for (int k = tid; k < kmax; k += 256)
        for (int p = 0; p < NP; p++) m[p] = fmaxf(m[p], sbuf[p][k]);
    for (int p = 0; p < NP; p++) {
        float v = m[p];
        for (int off = 32; off >= 1; off >>= 1)
            v = fmaxf(v, __shfl_xor(v, off));
        if (lane == 0) red[wid][p] = v;
    }
    __syncthreads();
    for (int p = 0; p < NP; p++)
        m[p] = fmaxf(fmaxf(red[0][p], red[1][p]), fmaxf(red[2][p], red[3][p]));
    __syncthreads();   // all reads of red done before reuse

    // exp + per-plane sum (overwrite sbuf with e)
    float lsum[NP] = {0.f, 0.f, 0.f, 0.f};
    for (int k = tid; k < kmax; k += 256) {
        for (int p = 0; p < NP; p++) {
            float e = __expf(sbuf[p][k] - m[p]);
            sbuf[p][k] = e;
            lsum[p] += e;
        }
    }
    for (int p = 0; p < NP; p++) {
        float v = lsum[p];
        for (int off = 32; off >= 1; off >>= 1)
            v += __shfl_xor(v, off);
        if (lane == 0) red[wid][p] = v;
    }
    __syncthreads();
    float inv[NP];
    for (int p = 0; p < NP; p++)
        inv[p] = 1.f / (red[0][p] + red[1][p] + red[2][p] + red[3][p]);

    // attn out + stash
    float* arow = out_attn + ((size_t)bh * L_SEQ + q) * L_SEQ;
    for (int k = tid; k < L_SEQ; k += 256) {
        float a = 0.f;
        if (k < kmax) {
            float best = sbuf[0][k] * inv[0];
            best = fmaxf(best, sbuf[1][k] * inv[1]);
            best = fmaxf(best, sbuf[2][k] * inv[2]);
            best = fmaxf(best, sbuf[3][k] * inv[3]);
            a = best;
        }
        arow[k] = a;
        abuf[k] = a;
    }
    __syncthreads();

    // context: d = lane dim, 4 k-groups
    int d = tid & 63, g = tid >> 6;
    float acc = 0.f;
    const float* Vb = V + (size_t)bh * L_SEQ * DK;
    for (int k = g; k < nk; k += 4)
        acc += abuf[k] * Vb[k * DK + d];
    float* part = &sbuf[0][0];
    part[tid] = acc;
    __syncthreads();
    if (tid < 64) {
        float cv = part[tid] + part[64 + tid] + part[128 + tid] + part[192 + tid];
        out_ctx[((size_t)bh * L_SEQ + q) * DK + tid] = cv;
    }
}

// ---------------------------------------------------------------------------
extern "C" void kernel_launch(void* const* d_in, const int* in_sizes, int n_in,
                              void* d_out, int out_size, void* d_ws, size_t ws_size,
                              hipStream_t stream) {
    const float* Q  = (const float*)d_in[0];
    const float* K  = (const float*)d_in[1];
    const float* V  = (const float*)d_in[2];
    // d_in[3] = attn_mask (causal, computed analytically)
    const float* w0 = (const float*)d_in[4];
    const float* b0 = (const float*)d_in[5];
    const float* w1 = (const float*)d_in[6];
    const float* b1 = (const float*)d_in[7];
    const float* w2 = (const float*)d_in[8];
    const float* b2 = (const float*)d_in[9];
    const float* w3 = (const float*)d_in[10];
    const float* b3 = (const float*)d_in[11];

    float* wsf = (float*)d_ws;
    float* Wt  = wsf;                  // 16*512*512      = 4,194,304 floats
    float* Qp  = wsf + 4194304;        // 16*4*1024*64    = 4,194,304 floats
    float* Kp  = wsf + 8388608;        // 4,194,304 floats

    float* out_ctx  = (float*)d_out;          // 2*8*1024*64  = 1,048,576
    float* out_attn = out_ctx + 1048576;      // 2*8*1024*1024

    transpose_w_kernel<<<dim3(8, 8, 16), 256, 0, stream>>>(w0, w1, w2, w3, Wt);
    conv_gemm_kernel<<<dim3(8, 8, 16), 256, 0, stream>>>(Q, K, Wt, b0, b1, b2, b3, Qp, Kp);
    attn_ctx_kernel<<<dim3(1024, 16), 256, 0, stream>>>(Qp, Kp, V, out_ctx, out_attn);
}

// Round 3
// 995.312 us; speedup vs baseline: 1.5322x; 1.5322x over previous
//
#include <hip/hip_runtime.h>
#include <math.h>

#define C_CH 512
#define L_SEQ 1024
#define DK 64
#define NP 4

typedef __attribute__((ext_vector_type(8))) short short8;
typedef __attribute__((ext_vector_type(4))) float f32x4;

__device__ __forceinline__ unsigned short f2bf(float f) {
    union { float f; unsigned u; } v; v.f = f;
    unsigned u = v.u;
    u += 0x7FFFu + ((u >> 16) & 1u);   // RNE
    return (unsigned short)(u >> 16);
}

// ---------------------------------------------------------------------------
// Kernel 1: transpose conv weights W[co][ci][t] -> Wt[t_global][ci][co] (fp32)
// ---------------------------------------------------------------------------
__global__ __launch_bounds__(256)
void transpose_w_kernel(const float* __restrict__ w0, const float* __restrict__ w1,
                        const float* __restrict__ w2, const float* __restrict__ w3,
                        float* __restrict__ Wt) {
    int z = blockIdx.z;
    int plane, t;
    if (z < 1)      { plane = 0; t = z; }
    else if (z < 4) { plane = 1; t = z - 1; }
    else if (z < 9) { plane = 2; t = z - 4; }
    else            { plane = 3; t = z - 9; }
    const float* W = (plane == 0) ? w0 : (plane == 1) ? w1 : (plane == 2) ? w2 : w3;
    const int f = (plane == 0) ? 1 : (plane == 1) ? 3 : (plane == 2) ? 5 : 7;

    int ci0 = blockIdx.x * 64;
    int co0 = blockIdx.y * 64;
    __shared__ float tile[64][65];
    int tid = threadIdx.x;
    int a  = tid & 63;
    int bq = tid >> 6;

    for (int rr = 0; rr < 16; rr++) {
        int co_l = bq + rr * 4;
        tile[a][co_l] = W[(size_t)(co0 + co_l) * (C_CH * f) + (size_t)(ci0 + a) * f + t];
    }
    __syncthreads();
    for (int rr = 0; rr < 16; rr++) {
        int ci_l = bq + rr * 4;
        Wt[((size_t)z * C_CH + (ci0 + ci_l)) * C_CH + co0 + a] = tile[ci_l][a];
    }
}

// ---------------------------------------------------------------------------
// Kernel 2: conv as fp32 GEMM, epilogue writes bf16 plane tensors.
// ---------------------------------------------------------------------------
__global__ __launch_bounds__(256)
void conv_gemm_kernel(const float* __restrict__ Qin, const float* __restrict__ Kin,
                      const float* __restrict__ Wt,
                      const float* __restrict__ b0, const float* __restrict__ b1,
                      const float* __restrict__ b2, const float* __restrict__ b3,
                      unsigned short* __restrict__ Qp, unsigned short* __restrict__ Kp) {
    const int fs[4]   = {1, 3, 5, 7};
    const int toff[4] = {0, 1, 4, 9};
    int z      = blockIdx.z;
    int b      = z & 1;
    int plane  = (z >> 1) & 3;
    int tensor = z >> 3;
    const float* X    = (tensor ? Kin : Qin) + (size_t)b * C_CH * L_SEQ;
    const float* bias = (plane == 0) ? b0 : (plane == 1) ? b1 : (plane == 2) ? b2 : b3;
    unsigned short* Out = tensor ? Kp : Qp;
    const int f   = fs[plane];
    const int pad = (f - 1) >> 1;

    int pos0 = blockIdx.x * 128;
    int co0  = blockIdx.y * 64;

    __shared__ __align__(16) float Asm[32][64];
    __shared__ __align__(16) float Bsm[32][128];

    int tid = threadIdx.x;
    int tx = tid & 15;
    int ty = tid >> 4;

    float acc[4][8];
    for (int i = 0; i < 4; i++)
        for (int j = 0; j < 8; j++) acc[i][j] = 0.f;

    for (int t = 0; t < f; t++) {
        const float* Wslice = Wt + (size_t)(toff[plane] + t) * C_CH * C_CH;
        int shift = t - pad;
        for (int cc = 0; cc < 16; cc++) {
            __syncthreads();
            {
                int colA = tid & 63, rowA = tid >> 6;
                for (int r = 0; r < 8; r++) {
                    int rr = rowA * 8 + r;
                    Asm[rr][colA] = Wslice[(size_t)(cc * 32 + rr) * C_CH + co0 + colA];
                }
                int colB = tid & 127, rowB = tid >> 7;
                int pg = pos0 + colB + shift;
                bool ok = (pg >= 0) && (pg < L_SEQ);
                for (int r = 0; r < 16; r++) {
                    int rr = rowB * 16 + r;
                    Bsm[rr][colB] = ok ? X[(size_t)(cc * 32 + rr) * L_SEQ + pg] : 0.f;
                }
            }
            __syncthreads();
#pragma unroll
            for (int kk = 0; kk < 32; kk++) {
                float4 a4  = *(const float4*)&Asm[kk][ty * 4];
                float4 bA  = *(const float4*)&Bsm[kk][tx * 4];
                float4 bB  = *(const float4*)&Bsm[kk][64 + tx * 4];
                float av[4] = {a4.x, a4.y, a4.z, a4.w};
                float bv[8] = {bA.x, bA.y, bA.z, bA.w, bB.x, bB.y, bB.z, bB.w};
                for (int i = 0; i < 4; i++)
                    for (int j = 0; j < 8; j++)
                        acc[i][j] = fmaf(av[i], bv[j], acc[i][j]);
            }
        }
    }

    int h = blockIdx.y;
    size_t pbase = ((size_t)(b * 8 + h) * NP + plane) * L_SEQ;
    for (int i = 0; i < 4; i++) {
        int c_local = ty * 4 + i;
        float bv = bias[co0 + c_local];
        int l0 = c_local * 16 + blockIdx.x * 2;
        ushort4 v0 = make_ushort4(f2bf(acc[i][0] + bv), f2bf(acc[i][1] + bv),
                                  f2bf(acc[i][2] + bv), f2bf(acc[i][3] + bv));
        ushort4 v1 = make_ushort4(f2bf(acc[i][4] + bv), f2bf(acc[i][5] + bv),
                                  f2bf(acc[i][6] + bv), f2bf(acc[i][7] + bv));
        *(ushort4*)&Out[(pbase + l0) * DK + tx * 4]     = v0;
        *(ushort4*)&Out[(pbase + l0 + 1) * DK + tx * 4] = v1;
    }
}

// ---------------------------------------------------------------------------
// Kernel 3: tiled two-pass flash attention with MFMA.
// Output (b2,h2): plane = b2*2 + (h2>>2), b_orig = (h2>>1)&1, h_orig = (h2&1)*4 + p
// slice(p) = (b_orig*8 + (h2&1)*4 + p)*4 + plane  (Qp/Kp bf16, [slice][l][64])
// grid: (16 qtiles, 16 bh), 256 threads = 4 waves, wave w owns q rows w*16..+15.
// ---------------------------------------------------------------------------
__global__ __launch_bounds__(256)
void attn_ctx_mfma(const unsigned short* __restrict__ Qb,
                   const unsigned short* __restrict__ Kb,
                   const float* __restrict__ V,
                   float* __restrict__ out_ctx, float* __restrict__ out_attn) {
    int qt = blockIdx.x, bh = blockIdx.y;
    int q0 = qt * 64;
    int b2 = bh >> 3, h2 = bh & 7;
    int plane  = b2 * 2 + (h2 >> 2);
    int b_orig = (h2 >> 1) & 1;
    int h_base = (h2 & 1) * 4;

    int tid  = threadIdx.x;
    int w    = tid >> 6;
    int lane = tid & 63;
    int l15  = lane & 15;
    int quad = lane >> 4;

    __shared__ __align__(16) unsigned short ast[64 * 80];   // a-tile bf16, stride 80
    __shared__ __align__(16) unsigned short vts[64 * 80];   // V^T tile bf16 [d][k]

    const unsigned short* kbase[NP];
    short8 qa[NP][2];
#pragma unroll
    for (int p = 0; p < NP; p++) {
        size_t slice = (size_t)((b_orig * 8 + h_base + p) * NP + plane);
        kbase[p] = Kb + slice * L_SEQ * DK;
        const unsigned short* qrow =
            Qb + (slice * L_SEQ + (size_t)(q0 + w * 16 + l15)) * DK + quad * 8;
        qa[p][0] = *(const short8*)(qrow);
        qa[p][1] = *(const short8*)(qrow + 32);
    }

    // ---------------- Pass 1: per-lane online (m, l) per plane ----------------
    float m[NP][4], l[NP][4];
#pragma unroll
    for (int p = 0; p < NP; p++)
        for (int r = 0; r < 4; r++) { m[p][r] = -1e30f; l[p][r] = 0.f; }

    for (int kt = 0; kt <= qt; kt++) {
        int k0 = kt * 64;
        bool diag = (kt == qt);
#pragma unroll
        for (int p = 0; p < NP; p++) {
            f32x4 c[4];
#pragma unroll
            for (int s = 0; s < 4; s++) {
                const unsigned short* kr =
                    kbase[p] + (size_t)(k0 + s * 16 + l15) * DK + quad * 8;
                short8 kb0 = *(const short8*)(kr);
                short8 kb1 = *(const short8*)(kr + 32);
                f32x4 acc = {0.f, 0.f, 0.f, 0.f};
                acc = __builtin_amdgcn_mfma_f32_16x16x32_bf16(qa[p][0], kb0, acc, 0, 0, 0);
                acc = __builtin_amdgcn_mfma_f32_16x16x32_bf16(qa[p][1], kb1, acc, 0, 0, 0);
                c[s] = acc;
            }
#pragma unroll
            for (int r = 0; r < 4; r++) {
                int row_local = quad * 4 + r + w * 16;
                float sv[4];
                float tm = -1e30f;
#pragma unroll
                for (int s = 0; s < 4; s++) {
                    float x = c[s][r] * 0.125f;
                    if (diag && (s * 16 + l15 > row_local)) x = -1e30f;
                    sv[s] = x;
                    tm = fmaxf(tm, x);
                }
                float mo = m[p][r];
                float mn = fmaxf(mo, tm);
                float fac = __expf(mo - mn);   // mo<=mn; (-1e30)-(-1e30)=0 -> 1, l=0 anyway
                float add = __expf(sv[0] - mn) + __expf(sv[1] - mn) +
                            __expf(sv[2] - mn) + __expf(sv[3] - mn);
                m[p][r] = mn;
                l[p][r] = l[p][r] * fac + add;
            }
        }
    }

    // reduce (m,l) across the 16 lanes sharing each q row
    float mrow[NP][4], inv[NP][4];
#pragma unroll
    for (int p = 0; p < NP; p++)
#pragma unroll
        for (int r = 0; r < 4; r++) {
            float mm = m[p][r];
            mm = fmaxf(mm, __shfl_xor(mm, 1));
            mm = fmaxf(mm, __shfl_xor(mm, 2));
            mm = fmaxf(mm, __shfl_xor(mm, 4));
            mm = fmaxf(mm, __shfl_xor(mm, 8));
            float ll = l[p][r] * __expf(m[p][r] - mm);  // kills garbage lanes
            ll += __shfl_xor(ll, 1);
            ll += __shfl_xor(ll, 2);
            ll += __shfl_xor(ll, 4);
            ll += __shfl_xor(ll, 8);
            mrow[p][r] = mm;
            inv[p][r]  = 1.f / ll;
        }

    // ---------------- Pass 2: attn = max_p softmax_p, write + context ----------
    f32x4 ctxc[4];
#pragma unroll
    for (int ds = 0; ds < 4; ds++) ctxc[ds] = (f32x4){0.f, 0.f, 0.f, 0.f};

    for (int kt = 0; kt <= qt; kt++) {
        int k0 = kt * 64;
        bool diag = (kt == qt);
        float aval[4][4];
#pragma unroll
        for (int s = 0; s < 4; s++)
            for (int r = 0; r < 4; r++) aval[s][r] = 0.f;

#pragma unroll
        for (int p = 0; p < NP; p++) {
            f32x4 c[4];
#pragma unroll
            for (int s = 0; s < 4; s++) {
                const unsigned short* kr =
                    kbase[p] + (size_t)(k0 + s * 16 + l15) * DK + quad * 8;
                short8 kb0 = *(const short8*)(kr);
                short8 kb1 = *(const short8*)(kr + 32);
                f32x4 acc = {0.f, 0.f, 0.f, 0.f};
                acc = __builtin_amdgcn_mfma_f32_16x16x32_bf16(qa[p][0], kb0, acc, 0, 0, 0);
                acc = __builtin_amdgcn_mfma_f32_16x16x32_bf16(qa[p][1], kb1, acc, 0, 0, 0);
                c[s] = acc;
            }
#pragma unroll
            for (int r = 0; r < 4; r++) {
                int row_local = quad * 4 + r + w * 16;
#pragma unroll
                for (int s = 0; s < 4; s++) {
                    float x = c[s][r] * 0.125f;
                    if (diag && (s * 16 + l15 > row_local)) x = -1e30f;
                    float e = __expf(x - mrow[p][r]) * inv[p][r];
                    aval[s][r] = fmaxf(aval[s][r], e);
                }
            }
        }

        // write attn (64B segments) + stash a-tile bf16 in LDS
#pragma unroll
        for (int s = 0; s < 4; s++)
#pragma unroll
            for (int r = 0; r < 4; r++) {
                int qloc = w * 16 + quad * 4 + r;
                int kg   = k0 + s * 16 + l15;
                out_attn[((size_t)bh * L_SEQ + q0 + qloc) * L_SEQ + kg] = aval[s][r];
                ast[qloc * 80 + s * 16 + l15] = f2bf(aval[s][r]);
            }

        // stage V^T tile bf16: vts[d][k] = V[k0+k][d]
        {
            int kl = tid >> 2, db = (tid & 3) * 16;
            const float* vr = V + ((size_t)bh * L_SEQ + k0 + kl) * DK + db;
            float vv[16];
            *(float4*)&vv[0]  = *(const float4*)(vr);
            *(float4*)&vv[4]  = *(const float4*)(vr + 4);
            *(float4*)&vv[8]  = *(const float4*)(vr + 8);
            *(float4*)&vv[12] = *(const float4*)(vr + 12);
#pragma unroll
            for (int j = 0; j < 16; j++)
                vts[(db + j) * 80 + kl] = f2bf(vv[j]);
        }
        __syncthreads();

        // context MFMAs: D[q][d] += a[q][k] * V[k][d]
        short8 af0 = *(const short8*)&ast[(w * 16 + l15) * 80 + quad * 8];
        short8 af1 = *(const short8*)&ast[(w * 16 + l15) * 80 + 32 + quad * 8];
#pragma unroll
        for (int ds = 0; ds < 4; ds++) {
            short8 bf0 = *(const short8*)&vts[(ds * 16 + l15) * 80 + quad * 8];
            short8 bf1 = *(const short8*)&vts[(ds * 16 + l15) * 80 + 32 + quad * 8];
            ctxc[ds] = __builtin_amdgcn_mfma_f32_16x16x32_bf16(af0, bf0, ctxc[ds], 0, 0, 0);
            ctxc[ds] = __builtin_amdgcn_mfma_f32_16x16x32_bf16(af1, bf1, ctxc[ds], 0, 0, 0);
        }
        __syncthreads();
    }

    // zero-fill attn cols beyond the causal region
    {
        int kz = (qt + 1) * 64;
        int ql = tid >> 2;
        float4 z = make_float4(0.f, 0.f, 0.f, 0.f);
        for (int k = kz + (tid & 3) * 4; k < L_SEQ; k += 16)
            *(float4*)&out_attn[((size_t)bh * L_SEQ + q0 + ql) * L_SEQ + k] = z;
    }

    // write context
#pragma unroll
    for (int ds = 0; ds < 4; ds++)
#pragma unroll
        for (int r = 0; r < 4; r++) {
            int qg = q0 + w * 16 + quad * 4 + r;
            out_ctx[((size_t)bh * L_SEQ + qg) * DK + ds * 16 + l15] = ctxc[ds][r];
        }
}

// ---------------------------------------------------------------------------
extern "C" void kernel_launch(void* const* d_in, const int* in_sizes, int n_in,
                              void* d_out, int out_size, void* d_ws, size_t ws_size,
                              hipStream_t stream) {
    const float* Q  = (const float*)d_in[0];
    const float* K  = (const float*)d_in[1];
    const float* V  = (const float*)d_in[2];
    const float* w0 = (const float*)d_in[4];
    const float* b0 = (const float*)d_in[5];
    const float* w1 = (const float*)d_in[6];
    const float* b1 = (const float*)d_in[7];
    const float* w2 = (const float*)d_in[8];
    const float* b2 = (const float*)d_in[9];
    const float* w3 = (const float*)d_in[10];
    const float* b3 = (const float*)d_in[11];

    float* wsf = (float*)d_ws;
    float* Wt = wsf;                                          // 4,194,304 floats
    unsigned short* Qp_b = (unsigned short*)(wsf + 4194304);  // 4,194,304 bf16
    unsigned short* Kp_b = (unsigned short*)(wsf + 6291456);  // 4,194,304 bf16

    float* out_ctx  = (float*)d_out;
    float* out_attn = out_ctx + 1048576;

    transpose_w_kernel<<<dim3(8, 8, 16), 256, 0, stream>>>(w0, w1, w2, w3, Wt);
    conv_gemm_kernel<<<dim3(8, 8, 16), 256, 0, stream>>>(Q, K, Wt, b0, b1, b2, b3, Qp_b, Kp_b);
    attn_ctx_mfma<<<dim3(16, 16), 256, 0, stream>>>(Qp_b, Kp_b, V, out_ctx, out_attn);
}

// Round 4
// 425.193 us; speedup vs baseline: 3.5866x; 2.3408x over previous
//
#include <hip/hip_runtime.h>
#include <math.h>

#define C_CH 512
#define L_SEQ 1024
#define DK 64
#define NP 4

typedef __attribute__((ext_vector_type(8))) short short8;
typedef __attribute__((ext_vector_type(4))) float f32x4;

__device__ __forceinline__ unsigned short f2bf(float f) {
    union { float f; unsigned u; } v; v.f = f;
    unsigned u = v.u;
    u += 0x7FFFu + ((u >> 16) & 1u);   // RNE
    return (unsigned short)(u >> 16);
}

// ---------------------------------------------------------------------------
// Prep 1: Wb[tg][co][ci] = bf16(W[co][ci][t]),  tg = toff[plane]+t (16 slices)
// grid (16 co-tiles of 32, 16 tg), 256 thr.
// ---------------------------------------------------------------------------
__global__ __launch_bounds__(256)
void prep_w_kernel(const float* __restrict__ w0, const float* __restrict__ w1,
                   const float* __restrict__ w2, const float* __restrict__ w3,
                   unsigned short* __restrict__ Wb) {
    int tg = blockIdx.y;
    int plane, t;
    if (tg < 1)      { plane = 0; t = tg; }
    else if (tg < 4) { plane = 1; t = tg - 1; }
    else if (tg < 9) { plane = 2; t = tg - 4; }
    else             { plane = 3; t = tg - 9; }
    const float* W = (plane == 0) ? w0 : (plane == 1) ? w1 : (plane == 2) ? w2 : w3;
    const int f = (plane == 0) ? 1 : (plane == 1) ? 3 : (plane == 2) ? 5 : 7;

    int co = blockIdx.x * 32 + (threadIdx.x >> 3);
    int c8 = threadIdx.x & 7;
    for (int it = 0; it < 8; it++) {
        int ci = c8 * 8 + it * 64;
        unsigned short o[8];
#pragma unroll
        for (int j = 0; j < 8; j++)
            o[j] = f2bf(W[(size_t)(co * C_CH + ci + j) * f + t]);
        *(short8*)&Wb[((size_t)tg * C_CH + co) * C_CH + ci] = *(short8*)o;
    }
}

// ---------------------------------------------------------------------------
// Prep 2: Xt[tb][pos+4][ci] = bf16(X[tb][ci][pos]); rows 0..3 / 1028..1031 zero.
// grid (16 pos-tiles of 64, 8 ci-tiles of 64, 4 tb), 256 thr.
// ---------------------------------------------------------------------------
__global__ __launch_bounds__(256)
void prep_x_kernel(const float* __restrict__ Qin, const float* __restrict__ Kin,
                   unsigned short* __restrict__ Xt) {
    int tb = blockIdx.z;           // tensor*2 + b
    int tensor = tb >> 1, b = tb & 1;
    const float* X = (tensor ? Kin : Qin) + (size_t)b * C_CH * L_SEQ;
    unsigned short* O = Xt + (size_t)tb * 1032 * C_CH;

    int pos0 = blockIdx.x * 64;
    int ci0  = blockIdx.y * 64;
    int tid = threadIdx.x;

    __shared__ float tile[64][65];
    int tx = tid & 15, ty = tid >> 4;
#pragma unroll
    for (int rr = 0; rr < 4; rr++) {
        int ci_l = ty + rr * 16;
        float4 v = *(const float4*)&X[(size_t)(ci0 + ci_l) * L_SEQ + pos0 + tx * 4];
        tile[tx * 4 + 0][ci_l] = v.x;
        tile[tx * 4 + 1][ci_l] = v.y;
        tile[tx * 4 + 2][ci_l] = v.z;
        tile[tx * 4 + 3][ci_l] = v.w;
    }
    __syncthreads();
#pragma unroll
    for (int pp = 0; pp < 2; pp++) {
        int pos_l = (tid >> 3) + pp * 32;
        int cg = (tid & 7) * 8;
        unsigned short o[8];
#pragma unroll
        for (int j = 0; j < 8; j++) o[j] = f2bf(tile[pos_l][cg + j]);
        *(short8*)&O[(size_t)(pos0 + pos_l + 4) * C_CH + ci0 + cg] = *(short8*)o;
    }
    // zero pads
    if (blockIdx.x == 0) {
        int r = tid >> 6, cc = tid & 63;
        O[(size_t)r * C_CH + ci0 + cc] = 0;
    }
    if (blockIdx.x == 15) {
        int r = tid >> 6, cc = tid & 63;
        O[(size_t)(1028 + r) * C_CH + ci0 + cc] = 0;
    }
}

// ---------------------------------------------------------------------------
// Conv as bf16-MFMA GEMM:  y[co][pos] = bias[co] + sum_t sum_ci
//   Wb[toff+t][co][ci] * Xt[tb][pos+t-pad+4][ci]
// Tile 128co x 128pos, 4 waves (2x2, each 64x64 = 4x4 MFMA 16x16x32 tiles).
// grid (16 combos FASTEST, 8 pos-tiles, 4 co-tiles).
// Epilogue: +bias, bf16, scatter to plane layout [slice][l][64].
// ---------------------------------------------------------------------------
__global__ __launch_bounds__(256)
void conv_mfma_kernel(const unsigned short* __restrict__ Xt,
                      const unsigned short* __restrict__ Wb,
                      const float* __restrict__ b0, const float* __restrict__ b1,
                      const float* __restrict__ b2, const float* __restrict__ b3,
                      unsigned short* __restrict__ Qp, unsigned short* __restrict__ Kp) {
    const int fs[4]   = {1, 3, 5, 7};
    const int toff[4] = {0, 1, 4, 9};
    int combo  = blockIdx.x;
    int b      = combo & 1;
    int plane  = (combo >> 1) & 3;
    int tensor = combo >> 3;
    const int f   = fs[plane];
    const int pad = (f - 1) >> 1;
    const float* bias = (plane == 0) ? b0 : (plane == 1) ? b1 : (plane == 2) ? b2 : b3;
    unsigned short* Out = tensor ? Kp : Qp;
    const unsigned short* Xbase = Xt + (size_t)(tensor * 2 + b) * 1032 * C_CH;

    int pos0 = blockIdx.y * 128;
    int co0  = blockIdx.z * 128;

    // LDS: row stride 40 shorts (80 B) -> 16B-aligned b128 ops, worst 2-way banks
    __shared__ __align__(16) unsigned short As[128 * 40];
    __shared__ __align__(16) unsigned short Bs[128 * 40];

    int tid  = threadIdx.x;
    int w    = tid >> 6;
    int lane = tid & 63;
    int l15  = lane & 15;
    int quad = lane >> 4;
    int wm = (w & 1) * 64;
    int wn = (w >> 1) * 64;

    int rowS = tid >> 2;      // 0..63
    int cS   = tid & 3;       // 16B column within 64B row chunk

    f32x4 acc[4][4];
#pragma unroll
    for (int mi = 0; mi < 4; mi++)
#pragma unroll
        for (int ni = 0; ni < 4; ni++) acc[mi][ni] = (f32x4){0.f, 0.f, 0.f, 0.f};

    for (int t = 0; t < f; t++) {
        const unsigned short* Wsl = Wb + ((size_t)(toff[plane] + t) * C_CH + co0) * C_CH;
        const unsigned short* Xsl = Xbase + (size_t)(pos0 + t - pad + 4) * C_CH;
        for (int cc = 0; cc < 16; cc++) {
            int kb = cc * 32;
            __syncthreads();
#pragma unroll
            for (int rep = 0; rep < 2; rep++) {
                int row = rowS + rep * 64;
                short8 va = *(const short8*)&Wsl[(size_t)row * C_CH + kb + cS * 8];
                *(short8*)&As[row * 40 + cS * 8] = va;
                short8 vb = *(const short8*)&Xsl[(size_t)row * C_CH + kb + cS * 8];
                *(short8*)&Bs[row * 40 + cS * 8] = vb;
            }
            __syncthreads();

            short8 af[4], bf[4];
#pragma unroll
            for (int mi = 0; mi < 4; mi++)
                af[mi] = *(const short8*)&As[(wm + mi * 16 + l15) * 40 + quad * 8];
#pragma unroll
            for (int ni = 0; ni < 4; ni++)
                bf[ni] = *(const short8*)&Bs[(wn + ni * 16 + l15) * 40 + quad * 8];
#pragma unroll
            for (int mi = 0; mi < 4; mi++)
#pragma unroll
                for (int ni = 0; ni < 4; ni++)
                    acc[mi][ni] = __builtin_amdgcn_mfma_f32_16x16x32_bf16(
                        af[mi], bf[ni], acc[mi][ni], 0, 0, 0);
        }
    }

    // epilogue: scatter to plane layout
#pragma unroll
    for (int mi = 0; mi < 4; mi++)
#pragma unroll
        for (int r = 0; r < 4; r++) {
            int co_l = wm + mi * 16 + quad * 4 + r;
            int co = co0 + co_l;
            int h = co >> 6, cl = co & 63;
            float bv = bias[co];
            size_t sbase = (size_t)((b * 8 + h) * NP + plane) * L_SEQ * DK;
#pragma unroll
            for (int ni = 0; ni < 4; ni++) {
                int pos = pos0 + wn + ni * 16 + l15;
                int l = cl * 16 + (pos >> 6);
                int d = pos & 63;
                Out[sbase + (size_t)l * DK + d] = f2bf(acc[mi][ni][r] + bv);
            }
        }
}

// ---------------------------------------------------------------------------
// Kernel 3: tiled two-pass flash attention with MFMA (unchanged from R3).
// ---------------------------------------------------------------------------
__global__ __launch_bounds__(256)
void attn_ctx_mfma(const unsigned short* __restrict__ Qb,
                   const unsigned short* __restrict__ Kb,
                   const float* __restrict__ V,
                   float* __restrict__ out_ctx, float* __restrict__ out_attn) {
    int qt = blockIdx.x, bh = blockIdx.y;
    int q0 = qt * 64;
    int b2 = bh >> 3, h2 = bh & 7;
    int plane  = b2 * 2 + (h2 >> 2);
    int b_orig = (h2 >> 1) & 1;
    int h_base = (h2 & 1) * 4;

    int tid  = threadIdx.x;
    int w    = tid >> 6;
    int lane = tid & 63;
    int l15  = lane & 15;
    int quad = lane >> 4;

    __shared__ __align__(16) unsigned short ast[64 * 80];
    __shared__ __align__(16) unsigned short vts[64 * 80];

    const unsigned short* kbase[NP];
    short8 qa[NP][2];
#pragma unroll
    for (int p = 0; p < NP; p++) {
        size_t slice = (size_t)((b_orig * 8 + h_base + p) * NP + plane);
        kbase[p] = Kb + slice * L_SEQ * DK;
        const unsigned short* qrow =
            Qb + (slice * L_SEQ + (size_t)(q0 + w * 16 + l15)) * DK + quad * 8;
        qa[p][0] = *(const short8*)(qrow);
        qa[p][1] = *(const short8*)(qrow + 32);
    }

    float m[NP][4], l[NP][4];
#pragma unroll
    for (int p = 0; p < NP; p++)
        for (int r = 0; r < 4; r++) { m[p][r] = -1e30f; l[p][r] = 0.f; }

    for (int kt = 0; kt <= qt; kt++) {
        int k0 = kt * 64;
        bool diag = (kt == qt);
#pragma unroll
        for (int p = 0; p < NP; p++) {
            f32x4 c[4];
#pragma unroll
            for (int s = 0; s < 4; s++) {
                const unsigned short* kr =
                    kbase[p] + (size_t)(k0 + s * 16 + l15) * DK + quad * 8;
                short8 kb0 = *(const short8*)(kr);
                short8 kb1 = *(const short8*)(kr + 32);
                f32x4 acc = {0.f, 0.f, 0.f, 0.f};
                acc = __builtin_amdgcn_mfma_f32_16x16x32_bf16(qa[p][0], kb0, acc, 0, 0, 0);
                acc = __builtin_amdgcn_mfma_f32_16x16x32_bf16(qa[p][1], kb1, acc, 0, 0, 0);
                c[s] = acc;
            }
#pragma unroll
            for (int r = 0; r < 4; r++) {
                int row_local = quad * 4 + r + w * 16;
                float sv[4];
                float tm = -1e30f;
#pragma unroll
                for (int s = 0; s < 4; s++) {
                    float x = c[s][r] * 0.125f;
                    if (diag && (s * 16 + l15 > row_local)) x = -1e30f;
                    sv[s] = x;
                    tm = fmaxf(tm, x);
                }
                float mo = m[p][r];
                float mn = fmaxf(mo, tm);
                float fac = __expf(mo - mn);
                float add = __expf(sv[0] - mn) + __expf(sv[1] - mn) +
                            __expf(sv[2] - mn) + __expf(sv[3] - mn);
                m[p][r] = mn;
                l[p][r] = l[p][r] * fac + add;
            }
        }
    }

    float mrow[NP][4], inv[NP][4];
#pragma unroll
    for (int p = 0; p < NP; p++)
#pragma unroll
        for (int r = 0; r < 4; r++) {
            float mm = m[p][r];
            mm = fmaxf(mm, __shfl_xor(mm, 1));
            mm = fmaxf(mm, __shfl_xor(mm, 2));
            mm = fmaxf(mm, __shfl_xor(mm, 4));
            mm = fmaxf(mm, __shfl_xor(mm, 8));
            float ll = l[p][r] * __expf(m[p][r] - mm);
            ll += __shfl_xor(ll, 1);
            ll += __shfl_xor(ll, 2);
            ll += __shfl_xor(ll, 4);
            ll += __shfl_xor(ll, 8);
            mrow[p][r] = mm;
            inv[p][r]  = 1.f / ll;
        }

    f32x4 ctxc[4];
#pragma unroll
    for (int ds = 0; ds < 4; ds++) ctxc[ds] = (f32x4){0.f, 0.f, 0.f, 0.f};

    for (int kt = 0; kt <= qt; kt++) {
        int k0 = kt * 64;
        bool diag = (kt == qt);
        float aval[4][4];
#pragma unroll
        for (int s = 0; s < 4; s++)
            for (int r = 0; r < 4; r++) aval[s][r] = 0.f;

#pragma unroll
        for (int p = 0; p < NP; p++) {
            f32x4 c[4];
#pragma unroll
            for (int s = 0; s < 4; s++) {
                const unsigned short* kr =
                    kbase[p] + (size_t)(k0 + s * 16 + l15) * DK + quad * 8;
                short8 kb0 = *(const short8*)(kr);
                short8 kb1 = *(const short8*)(kr + 32);
                f32x4 acc = {0.f, 0.f, 0.f, 0.f};
                acc = __builtin_amdgcn_mfma_f32_16x16x32_bf16(qa[p][0], kb0, acc, 0, 0, 0);
                acc = __builtin_amdgcn_mfma_f32_16x16x32_bf16(qa[p][1], kb1, acc, 0, 0, 0);
                c[s] = acc;
            }
#pragma unroll
            for (int r = 0; r < 4; r++) {
                int row_local = quad * 4 + r + w * 16;
#pragma unroll
                for (int s = 0; s < 4; s++) {
                    float x = c[s][r] * 0.125f;
                    if (diag && (s * 16 + l15 > row_local)) x = -1e30f;
                    float e = __expf(x - mrow[p][r]) * inv[p][r];
                    aval[s][r] = fmaxf(aval[s][r], e);
                }
            }
        }

#pragma unroll
        for (int s = 0; s < 4; s++)
#pragma unroll
            for (int r = 0; r < 4; r++) {
                int qloc = w * 16 + quad * 4 + r;
                int kg   = k0 + s * 16 + l15;
                out_attn[((size_t)bh * L_SEQ + q0 + qloc) * L_SEQ + kg] = aval[s][r];
                ast[qloc * 80 + s * 16 + l15] = f2bf(aval[s][r]);
            }

        {
            int kl = tid >> 2, db = (tid & 3) * 16;
            const float* vr = V + ((size_t)bh * L_SEQ + k0 + kl) * DK + db;
            float vv[16];
            *(float4*)&vv[0]  = *(const float4*)(vr);
            *(float4*)&vv[4]  = *(const float4*)(vr + 4);
            *(float4*)&vv[8]  = *(const float4*)(vr + 8);
            *(float4*)&vv[12] = *(const float4*)(vr + 12);
#pragma unroll
            for (int j = 0; j < 16; j++)
                vts[(db + j) * 80 + kl] = f2bf(vv[j]);
        }
        __syncthreads();

        short8 af0 = *(const short8*)&ast[(w * 16 + l15) * 80 + quad * 8];
        short8 af1 = *(const short8*)&ast[(w * 16 + l15) * 80 + 32 + quad * 8];
#pragma unroll
        for (int ds = 0; ds < 4; ds++) {
            short8 bf0 = *(const short8*)&vts[(ds * 16 + l15) * 80 + quad * 8];
            short8 bf1 = *(const short8*)&vts[(ds * 16 + l15) * 80 + 32 + quad * 8];
            ctxc[ds] = __builtin_amdgcn_mfma_f32_16x16x32_bf16(af0, bf0, ctxc[ds], 0, 0, 0);
            ctxc[ds] = __builtin_amdgcn_mfma_f32_16x16x32_bf16(af1, bf1, ctxc[ds], 0, 0, 0);
        }
        __syncthreads();
    }

    {
        int kz = (qt + 1) * 64;
        int ql = tid >> 2;
        float4 z = make_float4(0.f, 0.f, 0.f, 0.f);
        for (int k = kz + (tid & 3) * 4; k < L_SEQ; k += 16)
            *(float4*)&out_attn[((size_t)bh * L_SEQ + q0 + ql) * L_SEQ + k] = z;
    }

#pragma unroll
    for (int ds = 0; ds < 4; ds++)
#pragma unroll
        for (int r = 0; r < 4; r++) {
            int qg = q0 + w * 16 + quad * 4 + r;
            out_ctx[((size_t)bh * L_SEQ + qg) * DK + ds * 16 + l15] = ctxc[ds][r];
        }
}

// ---------------------------------------------------------------------------
extern "C" void kernel_launch(void* const* d_in, const int* in_sizes, int n_in,
                              void* d_out, int out_size, void* d_ws, size_t ws_size,
                              hipStream_t stream) {
    const float* Q  = (const float*)d_in[0];
    const float* K  = (const float*)d_in[1];
    const float* V  = (const float*)d_in[2];
    const float* w0 = (const float*)d_in[4];
    const float* b0 = (const float*)d_in[5];
    const float* w1 = (const float*)d_in[6];
    const float* b1 = (const float*)d_in[7];
    const float* w2 = (const float*)d_in[8];
    const float* b2 = (const float*)d_in[9];
    const float* w3 = (const float*)d_in[10];
    const float* b3 = (const float*)d_in[11];

    char* ws = (char*)d_ws;
    unsigned short* Wb = (unsigned short*)(ws);                  // 16*512*512*2  = 8,388,608 B
    unsigned short* Xt = (unsigned short*)(ws + 8388608);        // 4*1032*512*2  = 4,227,072 B
    unsigned short* Qp = (unsigned short*)(ws + 12615680);       // 8,388,608 B
    unsigned short* Kp = (unsigned short*)(ws + 21004288);       // 8,388,608 B

    float* out_ctx  = (float*)d_out;
    float* out_attn = out_ctx + 1048576;

    prep_w_kernel<<<dim3(16, 16), 256, 0, stream>>>(w0, w1, w2, w3, Wb);
    prep_x_kernel<<<dim3(16, 8, 4), 256, 0, stream>>>(Q, K, Xt);
    conv_mfma_kernel<<<dim3(16, 8, 4), 256, 0, stream>>>(Xt, Wb, b0, b1, b2, b3, Qp, Kp);
    attn_ctx_mfma<<<dim3(16, 16), 256, 0, stream>>>(Qp, Kp, V, out_ctx, out_attn);
}

// Round 5
// 393.558 us; speedup vs baseline: 3.8749x; 1.0804x over previous
//
#include <hip/hip_runtime.h>
#include <math.h>

#define C_CH 512
#define L_SEQ 1024
#define DK 64
#define NP 4

typedef __attribute__((ext_vector_type(8))) short short8;
typedef __attribute__((ext_vector_type(4))) float f32x4;

__device__ __forceinline__ unsigned short f2bf(float f) {
    union { float f; unsigned u; } v; v.f = f;
    unsigned u = v.u;
    u += 0x7FFFu + ((u >> 16) & 1u);   // RNE
    return (unsigned short)(u >> 16);
}

// ---------------------------------------------------------------------------
// Prep 1: Wb[tg][co][ci] = bf16(W[co][ci][t]),  tg = toff[plane]+t (16 slices)
// ---------------------------------------------------------------------------
__global__ __launch_bounds__(256)
void prep_w_kernel(const float* __restrict__ w0, const float* __restrict__ w1,
                   const float* __restrict__ w2, const float* __restrict__ w3,
                   unsigned short* __restrict__ Wb) {
    int tg = blockIdx.y;
    int plane, t;
    if (tg < 1)      { plane = 0; t = tg; }
    else if (tg < 4) { plane = 1; t = tg - 1; }
    else if (tg < 9) { plane = 2; t = tg - 4; }
    else             { plane = 3; t = tg - 9; }
    const float* W = (plane == 0) ? w0 : (plane == 1) ? w1 : (plane == 2) ? w2 : w3;
    const int f = (plane == 0) ? 1 : (plane == 1) ? 3 : (plane == 2) ? 5 : 7;

    int co = blockIdx.x * 32 + (threadIdx.x >> 3);
    int c8 = threadIdx.x & 7;
    for (int it = 0; it < 8; it++) {
        int ci = c8 * 8 + it * 64;
        unsigned short o[8];
#pragma unroll
        for (int j = 0; j < 8; j++)
            o[j] = f2bf(W[(size_t)(co * C_CH + ci + j) * f + t]);
        *(short8*)&Wb[((size_t)tg * C_CH + co) * C_CH + ci] = *(short8*)o;
    }
}

// ---------------------------------------------------------------------------
// Prep 2: Xt[tb][pos+4][ci] = bf16(X[tb][ci][pos]); rows 0..3 / 1028..1031 zero.
// ---------------------------------------------------------------------------
__global__ __launch_bounds__(256)
void prep_x_kernel(const float* __restrict__ Qin, const float* __restrict__ Kin,
                   unsigned short* __restrict__ Xt) {
    int tb = blockIdx.z;
    int tensor = tb >> 1, b = tb & 1;
    const float* X = (tensor ? Kin : Qin) + (size_t)b * C_CH * L_SEQ;
    unsigned short* O = Xt + (size_t)tb * 1032 * C_CH;

    int pos0 = blockIdx.x * 64;
    int ci0  = blockIdx.y * 64;
    int tid = threadIdx.x;

    __shared__ float tile[64][65];
    int tx = tid & 15, ty = tid >> 4;
#pragma unroll
    for (int rr = 0; rr < 4; rr++) {
        int ci_l = ty + rr * 16;
        float4 v = *(const float4*)&X[(size_t)(ci0 + ci_l) * L_SEQ + pos0 + tx * 4];
        tile[tx * 4 + 0][ci_l] = v.x;
        tile[tx * 4 + 1][ci_l] = v.y;
        tile[tx * 4 + 2][ci_l] = v.z;
        tile[tx * 4 + 3][ci_l] = v.w;
    }
    __syncthreads();
#pragma unroll
    for (int pp = 0; pp < 2; pp++) {
        int pos_l = (tid >> 3) + pp * 32;
        int cg = (tid & 7) * 8;
        unsigned short o[8];
#pragma unroll
        for (int j = 0; j < 8; j++) o[j] = f2bf(tile[pos_l][cg + j]);
        *(short8*)&O[(size_t)(pos0 + pos_l + 4) * C_CH + ci0 + cg] = *(short8*)o;
    }
    if (blockIdx.x == 0) {
        int r = tid >> 6, cc = tid & 63;
        O[(size_t)r * C_CH + ci0 + cc] = 0;
    }
    if (blockIdx.x == 15) {
        int r = tid >> 6, cc = tid & 63;
        O[(size_t)(1028 + r) * C_CH + ci0 + cc] = 0;
    }
}

// ---------------------------------------------------------------------------
// Conv as bf16-MFMA GEMM (unchanged from R4).
// ---------------------------------------------------------------------------
__global__ __launch_bounds__(256)
void conv_mfma_kernel(const unsigned short* __restrict__ Xt,
                      const unsigned short* __restrict__ Wb,
                      const float* __restrict__ b0, const float* __restrict__ b1,
                      const float* __restrict__ b2, const float* __restrict__ b3,
                      unsigned short* __restrict__ Qp, unsigned short* __restrict__ Kp) {
    const int fs[4]   = {1, 3, 5, 7};
    const int toff[4] = {0, 1, 4, 9};
    int combo  = blockIdx.x;
    int b      = combo & 1;
    int plane  = (combo >> 1) & 3;
    int tensor = combo >> 3;
    const int f   = fs[plane];
    const int pad = (f - 1) >> 1;
    const float* bias = (plane == 0) ? b0 : (plane == 1) ? b1 : (plane == 2) ? b2 : b3;
    unsigned short* Out = tensor ? Kp : Qp;
    const unsigned short* Xbase = Xt + (size_t)(tensor * 2 + b) * 1032 * C_CH;

    int pos0 = blockIdx.y * 128;
    int co0  = blockIdx.z * 128;

    __shared__ __align__(16) unsigned short As[128 * 40];
    __shared__ __align__(16) unsigned short Bs[128 * 40];

    int tid  = threadIdx.x;
    int w    = tid >> 6;
    int lane = tid & 63;
    int l15  = lane & 15;
    int quad = lane >> 4;
    int wm = (w & 1) * 64;
    int wn = (w >> 1) * 64;

    int rowS = tid >> 2;
    int cS   = tid & 3;

    f32x4 acc[4][4];
#pragma unroll
    for (int mi = 0; mi < 4; mi++)
#pragma unroll
        for (int ni = 0; ni < 4; ni++) acc[mi][ni] = (f32x4){0.f, 0.f, 0.f, 0.f};

    for (int t = 0; t < f; t++) {
        const unsigned short* Wsl = Wb + ((size_t)(toff[plane] + t) * C_CH + co0) * C_CH;
        const unsigned short* Xsl = Xbase + (size_t)(pos0 + t - pad + 4) * C_CH;
        for (int cc = 0; cc < 16; cc++) {
            int kb = cc * 32;
            __syncthreads();
#pragma unroll
            for (int rep = 0; rep < 2; rep++) {
                int row = rowS + rep * 64;
                short8 va = *(const short8*)&Wsl[(size_t)row * C_CH + kb + cS * 8];
                *(short8*)&As[row * 40 + cS * 8] = va;
                short8 vb = *(const short8*)&Xsl[(size_t)row * C_CH + kb + cS * 8];
                *(short8*)&Bs[row * 40 + cS * 8] = vb;
            }
            __syncthreads();

            short8 af[4], bf[4];
#pragma unroll
            for (int mi = 0; mi < 4; mi++)
                af[mi] = *(const short8*)&As[(wm + mi * 16 + l15) * 40 + quad * 8];
#pragma unroll
            for (int ni = 0; ni < 4; ni++)
                bf[ni] = *(const short8*)&Bs[(wn + ni * 16 + l15) * 40 + quad * 8];
#pragma unroll
            for (int mi = 0; mi < 4; mi++)
#pragma unroll
                for (int ni = 0; ni < 4; ni++)
                    acc[mi][ni] = __builtin_amdgcn_mfma_f32_16x16x32_bf16(
                        af[mi], bf[ni], acc[mi][ni], 0, 0, 0);
        }
    }

#pragma unroll
    for (int mi = 0; mi < 4; mi++)
#pragma unroll
        for (int r = 0; r < 4; r++) {
            int co_l = wm + mi * 16 + quad * 4 + r;
            int co = co0 + co_l;
            int h = co >> 6, cl = co & 63;
            float bv = bias[co];
            size_t sbase = (size_t)((b * 8 + h) * NP + plane) * L_SEQ * DK;
#pragma unroll
            for (int ni = 0; ni < 4; ni++) {
                int pos = pos0 + wn + ni * 16 + l15;
                int l = cl * 16 + (pos >> 6);
                int d = pos & 63;
                Out[sbase + (size_t)l * DK + d] = f2bf(acc[mi][ni][r] + bv);
            }
        }
}

// ---------------------------------------------------------------------------
// Attention stage A: partial (m,l) per plane per q-row over a 4-k-tile chunk.
// grid (4 kc, 16 qt, 16 bh), 256 thr. pstats[((bh*16+qt)*4+kc)*NP+p][row].
// ---------------------------------------------------------------------------
__global__ __launch_bounds__(256)
void attn_stats_kernel(const unsigned short* __restrict__ Qb,
                       const unsigned short* __restrict__ Kb,
                       float2* __restrict__ pstats) {
    int kc = blockIdx.x, qt = blockIdx.y, bh = blockIdx.z;
    int tid = threadIdx.x;
    size_t pbase = ((size_t)(bh * 16 + qt) * 4 + kc) * (NP * 64);

    if (kc * 4 > qt) {   // empty chunk: neutral stats
        pstats[pbase + tid] = make_float2(-1e30f, 0.f);
        return;
    }

    int q0 = qt * 64;
    int b2 = bh >> 3, h2 = bh & 7;
    int plane  = b2 * 2 + (h2 >> 2);
    int b_orig = (h2 >> 1) & 1;
    int h_base = (h2 & 1) * 4;
    int w = tid >> 6, lane = tid & 63, l15 = lane & 15, quad = lane >> 4;

    const unsigned short* kbase[NP];
    short8 qa[NP][2];
#pragma unroll
    for (int p = 0; p < NP; p++) {
        size_t slice = (size_t)((b_orig * 8 + h_base + p) * NP + plane);
        kbase[p] = Kb + slice * L_SEQ * DK;
        const unsigned short* qrow =
            Qb + (slice * L_SEQ + (size_t)(q0 + w * 16 + l15)) * DK + quad * 8;
        qa[p][0] = *(const short8*)(qrow);
        qa[p][1] = *(const short8*)(qrow + 32);
    }

    float m[NP][4], l[NP][4];
#pragma unroll
    for (int p = 0; p < NP; p++)
        for (int r = 0; r < 4; r++) { m[p][r] = -1e30f; l[p][r] = 0.f; }

    int kt1 = min(kc * 4 + 3, qt);
    for (int kt = kc * 4; kt <= kt1; kt++) {
        int k0 = kt * 64;
        bool diag = (kt == qt);
#pragma unroll
        for (int p = 0; p < NP; p++) {
            f32x4 c[4];
#pragma unroll
            for (int s = 0; s < 4; s++) {
                const unsigned short* kr =
                    kbase[p] + (size_t)(k0 + s * 16 + l15) * DK + quad * 8;
                short8 kb0 = *(const short8*)(kr);
                short8 kb1 = *(const short8*)(kr + 32);
                f32x4 acc = {0.f, 0.f, 0.f, 0.f};
                acc = __builtin_amdgcn_mfma_f32_16x16x32_bf16(qa[p][0], kb0, acc, 0, 0, 0);
                acc = __builtin_amdgcn_mfma_f32_16x16x32_bf16(qa[p][1], kb1, acc, 0, 0, 0);
                c[s] = acc;
            }
#pragma unroll
            for (int r = 0; r < 4; r++) {
                int row_local = quad * 4 + r + w * 16;
                float sv[4];
                float tm = -1e30f;
#pragma unroll
                for (int s = 0; s < 4; s++) {
                    float x = c[s][r] * 0.125f;
                    if (diag && (s * 16 + l15 > row_local)) x = -1e30f;
                    sv[s] = x;
                    tm = fmaxf(tm, x);
                }
                float mo = m[p][r];
                float mn = fmaxf(mo, tm);
                float fac = __expf(mo - mn);
                float add = __expf(sv[0] - mn) + __expf(sv[1] - mn) +
                            __expf(sv[2] - mn) + __expf(sv[3] - mn);
                m[p][r] = mn;
                l[p][r] = l[p][r] * fac + add;
            }
        }
    }

#pragma unroll
    for (int p = 0; p < NP; p++)
#pragma unroll
        for (int r = 0; r < 4; r++) {
            float mm = m[p][r];
            mm = fmaxf(mm, __shfl_xor(mm, 1));
            mm = fmaxf(mm, __shfl_xor(mm, 2));
            mm = fmaxf(mm, __shfl_xor(mm, 4));
            mm = fmaxf(mm, __shfl_xor(mm, 8));
            float ll = l[p][r] * __expf(m[p][r] - mm);
            ll += __shfl_xor(ll, 1);
            ll += __shfl_xor(ll, 2);
            ll += __shfl_xor(ll, 4);
            ll += __shfl_xor(ll, 8);
            if (l15 == 0)
                pstats[pbase + p * 64 + (w * 16 + quad * 4 + r)] = make_float2(mm, ll);
        }
}

// ---------------------------------------------------------------------------
// Attention stage B: combine 4 chunk partials -> (m, 1/l); zero out_ctx tile.
// grid (16 qt, 16 bh), 256 thr.
// ---------------------------------------------------------------------------
__global__ __launch_bounds__(256)
void attn_combine_kernel(const float2* __restrict__ pstats,
                         float2* __restrict__ fstats,
                         float* __restrict__ out_ctx) {
    int qt = blockIdx.x, bh = blockIdx.y;
    int tid = threadIdx.x;
    size_t base = ((size_t)(bh * 16 + qt) * 4) * (NP * 64);

    float2 s[4];
    float m = -1e30f;
#pragma unroll
    for (int kc = 0; kc < 4; kc++) {
        s[kc] = pstats[base + (size_t)kc * (NP * 64) + tid];
        m = fmaxf(m, s[kc].x);
    }
    float l = 0.f;
#pragma unroll
    for (int kc = 0; kc < 4; kc++)
        l += s[kc].y * __expf(s[kc].x - m);
    fstats[(size_t)(bh * 16 + qt) * (NP * 64) + tid] = make_float2(m, 1.f / l);

    // zero the context tile for this (bh, qt)
    int r = tid >> 2, c = (tid & 3) * 16;
    float4 z = make_float4(0.f, 0.f, 0.f, 0.f);
    size_t cbase = ((size_t)bh * L_SEQ + qt * 64 + r) * DK + c;
#pragma unroll
    for (int j = 0; j < 4; j++)
        *(float4*)&out_ctx[cbase + j * 4] = z;
}

// ---------------------------------------------------------------------------
// Attention stage C: one block per (kt, qt, bh) 64x64 tile. kt>qt: zero-fill.
// Else: scores (32 MFMA), attn=max_p softmax, write, PV partial (8 MFMA),
// atomicAdd into out_ctx. grid (16 kt, 16 qt, 16 bh), 256 thr.
// ---------------------------------------------------------------------------
__global__ __launch_bounds__(256)
void attn_apply_kernel(const unsigned short* __restrict__ Qb,
                       const unsigned short* __restrict__ Kb,
                       const float* __restrict__ V,
                       const float2* __restrict__ fstats,
                       float* __restrict__ out_ctx, float* __restrict__ out_attn) {
    int kt = blockIdx.x, qt = blockIdx.y, bh = blockIdx.z;
    int tid = threadIdx.x;
    int q0 = qt * 64, k0 = kt * 64;

    if (kt > qt) {   // masked region: zeros
        float4 z = make_float4(0.f, 0.f, 0.f, 0.f);
        size_t base = ((size_t)bh * L_SEQ + q0 + (tid >> 2)) * L_SEQ + k0 + (tid & 3) * 16;
#pragma unroll
        for (int j = 0; j < 4; j++)
            *(float4*)&out_attn[base + j * 4] = z;
        return;
    }

    int b2 = bh >> 3, h2 = bh & 7;
    int plane  = b2 * 2 + (h2 >> 2);
    int b_orig = (h2 >> 1) & 1;
    int h_base = (h2 & 1) * 4;
    int w = tid >> 6, lane = tid & 63, l15 = lane & 15, quad = lane >> 4;
    bool diag = (kt == qt);

    __shared__ float2 sstats[NP * 64];
    __shared__ __align__(16) unsigned short ast[64 * 80];
    __shared__ __align__(16) unsigned short vts[64 * 80];

    sstats[tid] = fstats[(size_t)(bh * 16 + qt) * (NP * 64) + tid];

    const unsigned short* kbase[NP];
    short8 qa[NP][2];
#pragma unroll
    for (int p = 0; p < NP; p++) {
        size_t slice = (size_t)((b_orig * 8 + h_base + p) * NP + plane);
        kbase[p] = Kb + slice * L_SEQ * DK;
        const unsigned short* qrow =
            Qb + (slice * L_SEQ + (size_t)(q0 + w * 16 + l15)) * DK + quad * 8;
        qa[p][0] = *(const short8*)(qrow);
        qa[p][1] = *(const short8*)(qrow + 32);
    }

    // stage V^T tile while stats settle
    {
        int kl = tid >> 2, db = (tid & 3) * 16;
        const float* vr = V + ((size_t)bh * L_SEQ + k0 + kl) * DK + db;
        float vv[16];
        *(float4*)&vv[0]  = *(const float4*)(vr);
        *(float4*)&vv[4]  = *(const float4*)(vr + 4);
        *(float4*)&vv[8]  = *(const float4*)(vr + 8);
        *(float4*)&vv[12] = *(const float4*)(vr + 12);
#pragma unroll
        for (int j = 0; j < 16; j++)
            vts[(db + j) * 80 + kl] = f2bf(vv[j]);
    }
    __syncthreads();   // sstats + vts visible

    float aval[4][4];
#pragma unroll
    for (int s = 0; s < 4; s++)
        for (int r = 0; r < 4; r++) aval[s][r] = 0.f;

#pragma unroll
    for (int p = 0; p < NP; p++) {
        f32x4 c[4];
#pragma unroll
        for (int s = 0; s < 4; s++) {
            const unsigned short* kr =
                kbase[p] + (size_t)(k0 + s * 16 + l15) * DK + quad * 8;
            short8 kb0 = *(const short8*)(kr);
            short8 kb1 = *(const short8*)(kr + 32);
            f32x4 acc = {0.f, 0.f, 0.f, 0.f};
            acc = __builtin_amdgcn_mfma_f32_16x16x32_bf16(qa[p][0], kb0, acc, 0, 0, 0);
            acc = __builtin_amdgcn_mfma_f32_16x16x32_bf16(qa[p][1], kb1, acc, 0, 0, 0);
            c[s] = acc;
        }
#pragma unroll
        for (int r = 0; r < 4; r++) {
            int row_local = quad * 4 + r + w * 16;
            float2 st = sstats[p * 64 + row_local];
#pragma unroll
            for (int s = 0; s < 4; s++) {
                float x = c[s][r] * 0.125f;
                if (diag && (s * 16 + l15 > row_local)) x = -1e30f;
                float e = __expf(x - st.x) * st.y;
                aval[s][r] = fmaxf(aval[s][r], e);
            }
        }
    }

    // write attn + stash a-tile bf16
#pragma unroll
    for (int s = 0; s < 4; s++)
#pragma unroll
        for (int r = 0; r < 4; r++) {
            int qloc = w * 16 + quad * 4 + r;
            int kg   = k0 + s * 16 + l15;
            out_attn[((size_t)bh * L_SEQ + q0 + qloc) * L_SEQ + kg] = aval[s][r];
            ast[qloc * 80 + s * 16 + l15] = f2bf(aval[s][r]);
        }
    __syncthreads();

    // PV partial: D[q][d] += a[q][k] * V[k][d]
    f32x4 ctxc[4];
#pragma unroll
    for (int ds = 0; ds < 4; ds++) ctxc[ds] = (f32x4){0.f, 0.f, 0.f, 0.f};
    short8 af0 = *(const short8*)&ast[(w * 16 + l15) * 80 + quad * 8];
    short8 af1 = *(const short8*)&ast[(w * 16 + l15) * 80 + 32 + quad * 8];
#pragma unroll
    for (int ds = 0; ds < 4; ds++) {
        short8 bf0 = *(const short8*)&vts[(ds * 16 + l15) * 80 + quad * 8];
        short8 bf1 = *(const short8*)&vts[(ds * 16 + l15) * 80 + 32 + quad * 8];
        ctxc[ds] = __builtin_amdgcn_mfma_f32_16x16x32_bf16(af0, bf0, ctxc[ds], 0, 0, 0);
        ctxc[ds] = __builtin_amdgcn_mfma_f32_16x16x32_bf16(af1, bf1, ctxc[ds], 0, 0, 0);
    }

#pragma unroll
    for (int ds = 0; ds < 4; ds++)
#pragma unroll
        for (int r = 0; r < 4; r++) {
            int qg = q0 + w * 16 + quad * 4 + r;
            unsafeAtomicAdd(&out_ctx[((size_t)bh * L_SEQ + qg) * DK + ds * 16 + l15],
                            ctxc[ds][r]);
        }
}

// ---------------------------------------------------------------------------
extern "C" void kernel_launch(void* const* d_in, const int* in_sizes, int n_in,
                              void* d_out, int out_size, void* d_ws, size_t ws_size,
                              hipStream_t stream) {
    const float* Q  = (const float*)d_in[0];
    const float* K  = (const float*)d_in[1];
    const float* V  = (const float*)d_in[2];
    const float* w0 = (const float*)d_in[4];
    const float* b0 = (const float*)d_in[5];
    const float* w1 = (const float*)d_in[6];
    const float* b1 = (const float*)d_in[7];
    const float* w2 = (const float*)d_in[8];
    const float* b2 = (const float*)d_in[9];
    const float* w3 = (const float*)d_in[10];
    const float* b3 = (const float*)d_in[11];

    char* ws = (char*)d_ws;
    unsigned short* Wb = (unsigned short*)(ws);                  // 8,388,608 B
    unsigned short* Xt = (unsigned short*)(ws + 8388608);        // 4,227,072 B
    unsigned short* Qp = (unsigned short*)(ws + 12615680);       // 8,388,608 B
    unsigned short* Kp = (unsigned short*)(ws + 21004288);       // 8,388,608 B
    // stats alias the Xt region (Xt is dead after conv_mfma):
    float2* pstats = (float2*)(ws + 8388608);                    // 2,097,152 B
    float2* fstats = (float2*)(ws + 8388608 + 2097152);          //   524,288 B

    float* out_ctx  = (float*)d_out;
    float* out_attn = out_ctx + 1048576;

    prep_w_kernel<<<dim3(16, 16), 256, 0, stream>>>(w0, w1, w2, w3, Wb);
    prep_x_kernel<<<dim3(16, 8, 4), 256, 0, stream>>>(Q, K, Xt);
    conv_mfma_kernel<<<dim3(16, 8, 4), 256, 0, stream>>>(Xt, Wb, b0, b1, b2, b3, Qp, Kp);
    attn_stats_kernel<<<dim3(4, 16, 16), 256, 0, stream>>>(Qp, Kp, pstats);
    attn_combine_kernel<<<dim3(16, 16), 256, 0, stream>>>(pstats, fstats, out_ctx);
    attn_apply_kernel<<<dim3(16, 16, 16), 256, 0, stream>>>(Qp, Kp, V, fstats,
                                                            out_ctx, out_attn);
}

// Round 6
// 365.613 us; speedup vs baseline: 4.1711x; 1.0764x over previous
//
#include <hip/hip_runtime.h>
#include <math.h>

#define C_CH 512
#define L_SEQ 1024
#define DK 64
#define NP 4
#define SC2 0.1803368801111f   // 0.125 * log2(e)

typedef __attribute__((ext_vector_type(8))) short short8;
typedef __attribute__((ext_vector_type(4))) float f32x4;

__device__ __forceinline__ unsigned short f2bf(float f) {
    union { float f; unsigned u; } v; v.f = f;
    unsigned u = v.u;
    u += 0x7FFFu + ((u >> 16) & 1u);   // RNE
    return (unsigned short)(u >> 16);
}

// ---------------------------------------------------------------------------
// Prep 1: Wb[tg][co][ci] = bf16(W[co][ci][t]),  tg = toff[plane]+t (16 slices)
// ---------------------------------------------------------------------------
__global__ __launch_bounds__(256)
void prep_w_kernel(const float* __restrict__ w0, const float* __restrict__ w1,
                   const float* __restrict__ w2, const float* __restrict__ w3,
                   unsigned short* __restrict__ Wb) {
    int tg = blockIdx.y;
    int plane, t;
    if (tg < 1)      { plane = 0; t = tg; }
    else if (tg < 4) { plane = 1; t = tg - 1; }
    else if (tg < 9) { plane = 2; t = tg - 4; }
    else             { plane = 3; t = tg - 9; }
    const float* W = (plane == 0) ? w0 : (plane == 1) ? w1 : (plane == 2) ? w2 : w3;
    const int f = (plane == 0) ? 1 : (plane == 1) ? 3 : (plane == 2) ? 5 : 7;

    int co = blockIdx.x * 32 + (threadIdx.x >> 3);
    int c8 = threadIdx.x & 7;
    for (int it = 0; it < 8; it++) {
        int ci = c8 * 8 + it * 64;
        unsigned short o[8];
#pragma unroll
        for (int j = 0; j < 8; j++)
            o[j] = f2bf(W[(size_t)(co * C_CH + ci + j) * f + t]);
        *(short8*)&Wb[((size_t)tg * C_CH + co) * C_CH + ci] = *(short8*)o;
    }
}

// ---------------------------------------------------------------------------
// Prep 2: Xt[tb][pos+4][ci] = bf16(X[tb][ci][pos]); rows 0..3 / 1028..1031 zero.
// ---------------------------------------------------------------------------
__global__ __launch_bounds__(256)
void prep_x_kernel(const float* __restrict__ Qin, const float* __restrict__ Kin,
                   unsigned short* __restrict__ Xt) {
    int tb = blockIdx.z;
    int tensor = tb >> 1, b = tb & 1;
    const float* X = (tensor ? Kin : Qin) + (size_t)b * C_CH * L_SEQ;
    unsigned short* O = Xt + (size_t)tb * 1032 * C_CH;

    int pos0 = blockIdx.x * 64;
    int ci0  = blockIdx.y * 64;
    int tid = threadIdx.x;

    __shared__ float tile[64][65];
    int tx = tid & 15, ty = tid >> 4;
#pragma unroll
    for (int rr = 0; rr < 4; rr++) {
        int ci_l = ty + rr * 16;
        float4 v = *(const float4*)&X[(size_t)(ci0 + ci_l) * L_SEQ + pos0 + tx * 4];
        tile[tx * 4 + 0][ci_l] = v.x;
        tile[tx * 4 + 1][ci_l] = v.y;
        tile[tx * 4 + 2][ci_l] = v.z;
        tile[tx * 4 + 3][ci_l] = v.w;
    }
    __syncthreads();
#pragma unroll
    for (int pp = 0; pp < 2; pp++) {
        int pos_l = (tid >> 3) + pp * 32;
        int cg = (tid & 7) * 8;
        unsigned short o[8];
#pragma unroll
        for (int j = 0; j < 8; j++) o[j] = f2bf(tile[pos_l][cg + j]);
        *(short8*)&O[(size_t)(pos0 + pos_l + 4) * C_CH + ci0 + cg] = *(short8*)o;
    }
    if (blockIdx.x == 0) {
        int r = tid >> 6, cc = tid & 63;
        O[(size_t)r * C_CH + ci0 + cc] = 0;
    }
    if (blockIdx.x == 15) {
        int r = tid >> 6, cc = tid & 63;
        O[(size_t)(1028 + r) * C_CH + ci0 + cc] = 0;
    }
}

// ---------------------------------------------------------------------------
// Conv: paired-tile bf16-MFMA GEMM. 256 blocks, each does TWO 128co x 128pos
// tiles whose f's sum to 8 (f1+f7 or f3+f5) -> perfectly uniform work.
// LDS XOR-swizzled: [64 lines][8 slots of 16B], slot ^= (line&7): 2-way banks.
// Register prefetch of next K-chunk overlaps global latency with MFMAs.
// ---------------------------------------------------------------------------
__global__ __launch_bounds__(256)
void conv_pair_kernel(const unsigned short* __restrict__ Xt,
                      const unsigned short* __restrict__ Wb,
                      const float* __restrict__ b0, const float* __restrict__ b1,
                      const float* __restrict__ b2, const float* __restrict__ b3,
                      unsigned short* __restrict__ Qp, unsigned short* __restrict__ Kp) {
    const int fs[4]   = {1, 3, 5, 7};
    const int toff[4] = {0, 1, 4, 9};
    int blk = blockIdx.x;
    int cls = blk >> 7;           // 0: planes {0,3}, 1: planes {1,2}
    int idx = blk & 127;
    int co0  = (idx & 3) * 128;
    int pos0 = ((idx >> 2) & 7) * 128;
    int tb   = idx >> 5;
    int tensor = tb >> 1, b = tb & 1;
    unsigned short* Out = tensor ? Kp : Qp;
    const unsigned short* Xbase = Xt + (size_t)tb * 1032 * C_CH;

    __shared__ __align__(16) unsigned short As[4096];
    __shared__ __align__(16) unsigned short Bs[4096];

    int tid  = threadIdx.x;
    int w    = tid >> 6;
    int lane = tid & 63;
    int l15  = lane & 15;
    int quad = lane >> 4;
    int wm = (w & 1) * 64;
    int wn = (w >> 1) * 64;
    int rowL = tid >> 2;          // 0..63
    int cS   = tid & 3;

    int woff[2];
#pragma unroll
    for (int rep = 0; rep < 2; rep++) {
        int r = rowL + rep * 64;
        int line = r >> 1;
        int sl = (((r & 1) << 2) | cS) ^ (line & 7);
        woff[rep] = line * 64 + sl * 8;
    }
    int aoff[4], boff[4];
#pragma unroll
    for (int mi = 0; mi < 4; mi++) {
        int r = wm + mi * 16 + l15;
        int line = r >> 1;
        aoff[mi] = line * 64 + ((((r & 1) << 2) | quad) ^ (line & 7)) * 8;
        int r2 = wn + mi * 16 + l15;
        int line2 = r2 >> 1;
        boff[mi] = line2 * 64 + ((((r2 & 1) << 2) | quad) ^ (line2 & 7)) * 8;
    }

    for (int ti = 0; ti < 2; ti++) {
        int plane = (cls == 0) ? (ti == 0 ? 0 : 3) : (ti == 0 ? 1 : 2);
        const int f   = fs[plane];
        const int pad = (f - 1) >> 1;
        const float* bias = (plane == 0) ? b0 : (plane == 1) ? b1 : (plane == 2) ? b2 : b3;
        const int n = f * 16;

        f32x4 acc[4][4];
#pragma unroll
        for (int mi = 0; mi < 4; mi++)
#pragma unroll
            for (int ni = 0; ni < 4; ni++) acc[mi][ni] = (f32x4){0.f, 0.f, 0.f, 0.f};

        short8 pA[2], pB[2];
        {
            const unsigned short* Wsl = Wb + ((size_t)toff[plane] * C_CH + co0) * C_CH;
            const unsigned short* Xsl = Xbase + (size_t)(pos0 - pad + 4) * C_CH;
#pragma unroll
            for (int rep = 0; rep < 2; rep++) {
                int r = rowL + rep * 64;
                pA[rep] = *(const short8*)&Wsl[(size_t)r * C_CH + cS * 8];
                pB[rep] = *(const short8*)&Xsl[(size_t)r * C_CH + cS * 8];
            }
        }

        for (int it = 0; it < n; it++) {
            __syncthreads();
            *(short8*)&As[woff[0]] = pA[0];
            *(short8*)&As[woff[1]] = pA[1];
            *(short8*)&Bs[woff[0]] = pB[0];
            *(short8*)&Bs[woff[1]] = pB[1];
            __syncthreads();

            if (it + 1 < n) {
                int t = (it + 1) >> 4, cc = (it + 1) & 15;
                const unsigned short* Wsl =
                    Wb + ((size_t)(toff[plane] + t) * C_CH + co0) * C_CH + cc * 32;
                const unsigned short* Xsl =
                    Xbase + (size_t)(pos0 + t - pad + 4) * C_CH + cc * 32;
#pragma unroll
                for (int rep = 0; rep < 2; rep++) {
                    int r = rowL + rep * 64;
                    pA[rep] = *(const short8*)&Wsl[(size_t)r * C_CH + cS * 8];
                    pB[rep] = *(const short8*)&Xsl[(size_t)r * C_CH + cS * 8];
                }
            }

            short8 af[4], bf[4];
#pragma unroll
            for (int mi = 0; mi < 4; mi++) af[mi] = *(const short8*)&As[aoff[mi]];
#pragma unroll
            for (int ni = 0; ni < 4; ni++) bf[ni] = *(const short8*)&Bs[boff[ni]];
#pragma unroll
            for (int mi = 0; mi < 4; mi++)
#pragma unroll
                for (int ni = 0; ni < 4; ni++)
                    acc[mi][ni] = __builtin_amdgcn_mfma_f32_16x16x32_bf16(
                        af[mi], bf[ni], acc[mi][ni], 0, 0, 0);
        }

        // epilogue: scatter to plane layout
#pragma unroll
        for (int mi = 0; mi < 4; mi++)
#pragma unroll
            for (int r = 0; r < 4; r++) {
                int co = co0 + wm + mi * 16 + quad * 4 + r;
                int h = co >> 6, cl = co & 63;
                float bv = bias[co];
                size_t sbase = (size_t)((b * 8 + h) * NP + plane) * L_SEQ * DK;
#pragma unroll
                for (int ni = 0; ni < 4; ni++) {
                    int pos = pos0 + wn + ni * 16 + l15;
                    int l = cl * 16 + (pos >> 6);
                    int d = pos & 63;
                    Out[sbase + (size_t)l * DK + d] = f2bf(acc[mi][ni][r] + bv);
                }
            }
    }
}

// ---------------------------------------------------------------------------
// Attention stage A: partial l = sum exp2(s2) per plane per q-row (no max:
// scores are O(10) in log2 space, fp32 sum is safe). grid (4 kc, 16 qt, 16 bh).
// ---------------------------------------------------------------------------
__global__ __launch_bounds__(256)
void attn_stats_kernel(const unsigned short* __restrict__ Qb,
                       const unsigned short* __restrict__ Kb,
                       float* __restrict__ pstats) {
    int kc = blockIdx.x, qt = blockIdx.y, bh = blockIdx.z;
    int tid = threadIdx.x;
    size_t pbase = ((size_t)(bh * 16 + qt) * 4 + kc) * (NP * 64);

    if (kc * 4 > qt) { pstats[pbase + tid] = 0.f; return; }

    int q0 = qt * 64;
    int b2 = bh >> 3, h2 = bh & 7;
    int plane  = b2 * 2 + (h2 >> 2);
    int b_orig = (h2 >> 1) & 1;
    int h_base = (h2 & 1) * 4;
    int w = tid >> 6, lane = tid & 63, l15 = lane & 15, quad = lane >> 4;

    const unsigned short* kbase[NP];
    short8 qa[NP][2];
#pragma unroll
    for (int p = 0; p < NP; p++) {
        size_t slice = (size_t)((b_orig * 8 + h_base + p) * NP + plane);
        kbase[p] = Kb + slice * L_SEQ * DK;
        const unsigned short* qrow =
            Qb + (slice * L_SEQ + (size_t)(q0 + w * 16 + l15)) * DK + quad * 8;
        qa[p][0] = *(const short8*)(qrow);
        qa[p][1] = *(const short8*)(qrow + 32);
    }

    float l[NP][4];
#pragma unroll
    for (int p = 0; p < NP; p++)
        for (int r = 0; r < 4; r++) l[p][r] = 0.f;

    int kt1 = min(kc * 4 + 3, qt);
    for (int kt = kc * 4; kt <= kt1; kt++) {
        int k0 = kt * 64;
        bool diag = (kt == qt);
#pragma unroll
        for (int p = 0; p < NP; p++) {
            f32x4 c[4];
#pragma unroll
            for (int s = 0; s < 4; s++) {
                const unsigned short* kr =
                    kbase[p] + (size_t)(k0 + s * 16 + l15) * DK + quad * 8;
                short8 kb0 = *(const short8*)(kr);
                short8 kb1 = *(const short8*)(kr + 32);
                f32x4 acc = {0.f, 0.f, 0.f, 0.f};
                acc = __builtin_amdgcn_mfma_f32_16x16x32_bf16(qa[p][0], kb0, acc, 0, 0, 0);
                acc = __builtin_amdgcn_mfma_f32_16x16x32_bf16(qa[p][1], kb1, acc, 0, 0, 0);
                c[s] = acc;
            }
#pragma unroll
            for (int r = 0; r < 4; r++) {
                int row_local = quad * 4 + r + w * 16;
#pragma unroll
                for (int s = 0; s < 4; s++) {
                    float x = c[s][r] * SC2;
                    if (diag && (s * 16 + l15 > row_local)) x = -1e30f;
                    l[p][r] += exp2f(x);
                }
            }
        }
    }

#pragma unroll
    for (int p = 0; p < NP; p++)
#pragma unroll
        for (int r = 0; r < 4; r++) {
            float ll = l[p][r];
            ll += __shfl_xor(ll, 1);
            ll += __shfl_xor(ll, 2);
            ll += __shfl_xor(ll, 4);
            ll += __shfl_xor(ll, 8);
            if (l15 == 0)
                pstats[pbase + p * 64 + (w * 16 + quad * 4 + r)] = ll;
        }
}

// ---------------------------------------------------------------------------
// Stage B: z = log2(sum_kc l); zero out_ctx tile. grid (16 qt, 16 bh).
// ---------------------------------------------------------------------------
__global__ __launch_bounds__(256)
void attn_combine_kernel(const float* __restrict__ pstats,
                         float* __restrict__ fstats,
                         float* __restrict__ out_ctx) {
    int qt = blockIdx.x, bh = blockIdx.y;
    int tid = threadIdx.x;
    size_t base = ((size_t)(bh * 16 + qt) * 4) * (NP * 64);

    float l = 0.f;
#pragma unroll
    for (int kc = 0; kc < 4; kc++)
        l += pstats[base + (size_t)kc * (NP * 64) + tid];
    fstats[(size_t)(bh * 16 + qt) * (NP * 64) + tid] = __log2f(l);

    int r = tid >> 2, c = (tid & 3) * 16;
    float4 z = make_float4(0.f, 0.f, 0.f, 0.f);
    size_t cbase = ((size_t)bh * L_SEQ + qt * 64 + r) * DK + c;
#pragma unroll
    for (int j = 0; j < 4; j++)
        *(float4*)&out_ctx[cbase + j * 4] = z;
}

// ---------------------------------------------------------------------------
// Stage C: 4 kt-tiles per block; attn = exp2(max_p(s2_p - z_p)); ctx acc in
// registers across tiles -> one atomic set. grid (4 kc, 16 qt, 16 bh).
// ---------------------------------------------------------------------------
__global__ __launch_bounds__(256)
void attn_apply_kernel(const unsigned short* __restrict__ Qb,
                       const unsigned short* __restrict__ Kb,
                       const float* __restrict__ V,
                       const float* __restrict__ fstats,
                       float* __restrict__ out_ctx, float* __restrict__ out_attn) {
    int kc = blockIdx.x, qt = blockIdx.y, bh = blockIdx.z;
    int tid = threadIdx.x;
    int q0 = qt * 64;
    bool any = (kc * 4 <= qt);

    int b2 = bh >> 3, h2 = bh & 7;
    int plane  = b2 * 2 + (h2 >> 2);
    int b_orig = (h2 >> 1) & 1;
    int h_base = (h2 & 1) * 4;
    int w = tid >> 6, lane = tid & 63, l15 = lane & 15, quad = lane >> 4;

    __shared__ float zsm[NP * 64];
    __shared__ __align__(16) unsigned short ast[64 * 80];
    __shared__ __align__(16) unsigned short vts[64 * 80];

    const unsigned short* kbase[NP];
    short8 qa[NP][2];
    if (any) {
        zsm[tid] = fstats[(size_t)(bh * 16 + qt) * (NP * 64) + tid];
#pragma unroll
        for (int p = 0; p < NP; p++) {
            size_t slice = (size_t)((b_orig * 8 + h_base + p) * NP + plane);
            kbase[p] = Kb + slice * L_SEQ * DK;
            const unsigned short* qrow =
                Qb + (slice * L_SEQ + (size_t)(q0 + w * 16 + l15)) * DK + quad * 8;
            qa[p][0] = *(const short8*)(qrow);
            qa[p][1] = *(const short8*)(qrow + 32);
        }
    }

    f32x4 ctxc[4];
#pragma unroll
    for (int ds = 0; ds < 4; ds++) ctxc[ds] = (f32x4){0.f, 0.f, 0.f, 0.f};

    for (int k4 = 0; k4 < 4; k4++) {
        int kt = kc * 4 + k4;
        int k0 = kt * 64;

        if (kt > qt) {   // masked region: zero-fill attn
            float4 z = make_float4(0.f, 0.f, 0.f, 0.f);
            size_t abase = ((size_t)bh * L_SEQ + q0) * L_SEQ + k0;
#pragma unroll
            for (int j = 0; j < 4; j++) {
                int flat = tid + j * 256;
                *(float4*)&out_attn[abase + (size_t)(flat >> 4) * L_SEQ + (flat & 15) * 4] = z;
            }
            continue;
        }
        bool diag = (kt == qt);

        __syncthreads();   // protect previous iter's ast/vts reads; zsm visible

        // stage V^T tile bf16
        {
            int kl = tid >> 2, db = (tid & 3) * 16;
            const float* vr = V + ((size_t)bh * L_SEQ + k0 + kl) * DK + db;
            float vv[16];
            *(float4*)&vv[0]  = *(const float4*)(vr);
            *(float4*)&vv[4]  = *(const float4*)(vr + 4);
            *(float4*)&vv[8]  = *(const float4*)(vr + 8);
            *(float4*)&vv[12] = *(const float4*)(vr + 12);
#pragma unroll
            for (int j = 0; j < 16; j++)
                vts[(db + j) * 80 + kl] = f2bf(vv[j]);
        }

        // scores -> run = max_p (s2_p - z_p)
        float run[4][4];
#pragma unroll
        for (int s = 0; s < 4; s++)
            for (int r = 0; r < 4; r++) run[s][r] = -1e30f;

#pragma unroll
        for (int p = 0; p < NP; p++) {
            f32x4 c[4];
#pragma unroll
            for (int s = 0; s < 4; s++) {
                const unsigned short* kr =
                    kbase[p] + (size_t)(k0 + s * 16 + l15) * DK + quad * 8;
                short8 kb0 = *(const short8*)(kr);
                short8 kb1 = *(const short8*)(kr + 32);
                f32x4 acc = {0.f, 0.f, 0.f, 0.f};
                acc = __builtin_amdgcn_mfma_f32_16x16x32_bf16(qa[p][0], kb0, acc, 0, 0, 0);
                acc = __builtin_amdgcn_mfma_f32_16x16x32_bf16(qa[p][1], kb1, acc, 0, 0, 0);
                c[s] = acc;
            }
#pragma unroll
            for (int r = 0; r < 4; r++) {
                float zp = zsm[p * 64 + (quad * 4 + r + w * 16)];
#pragma unroll
                for (int s = 0; s < 4; s++)
                    run[s][r] = fmaxf(run[s][r], c[s][r] * SC2 - zp);
            }
        }

        // attn values, write + stash
#pragma unroll
        for (int s = 0; s < 4; s++)
#pragma unroll
            for (int r = 0; r < 4; r++) {
                int qloc = w * 16 + quad * 4 + r;
                bool masked = diag && (s * 16 + l15 > qloc);
                float a = masked ? 0.f : exp2f(run[s][r]);
                out_attn[((size_t)bh * L_SEQ + q0 + qloc) * L_SEQ + k0 + s * 16 + l15] = a;
                ast[qloc * 80 + s * 16 + l15] = f2bf(a);
            }
        __syncthreads();

        // PV partial into register accumulator
        short8 af0 = *(const short8*)&ast[(w * 16 + l15) * 80 + quad * 8];
        short8 af1 = *(const short8*)&ast[(w * 16 + l15) * 80 + 32 + quad * 8];
#pragma unroll
        for (int ds = 0; ds < 4; ds++) {
            short8 bf0 = *(const short8*)&vts[(ds * 16 + l15) * 80 + quad * 8];
            short8 bf1 = *(const short8*)&vts[(ds * 16 + l15) * 80 + 32 + quad * 8];
            ctxc[ds] = __builtin_amdgcn_mfma_f32_16x16x32_bf16(af0, bf0, ctxc[ds], 0, 0, 0);
            ctxc[ds] = __builtin_amdgcn_mfma_f32_16x16x32_bf16(af1, bf1, ctxc[ds], 0, 0, 0);
        }
    }

    if (any) {
#pragma unroll
        for (int ds = 0; ds < 4; ds++)
#pragma unroll
            for (int r = 0; r < 4; r++) {
                int qg = q0 + w * 16 + quad * 4 + r;
                unsafeAtomicAdd(&out_ctx[((size_t)bh * L_SEQ + qg) * DK + ds * 16 + l15],
                                ctxc[ds][r]);
            }
    }
}

// ---------------------------------------------------------------------------
extern "C" void kernel_launch(void* const* d_in, const int* in_sizes, int n_in,
                              void* d_out, int out_size, void* d_ws, size_t ws_size,
                              hipStream_t stream) {
    const float* Q  = (const float*)d_in[0];
    const float* K  = (const float*)d_in[1];
    const float* V  = (const float*)d_in[2];
    const float* w0 = (const float*)d_in[4];
    const float* b0 = (const float*)d_in[5];
    const float* w1 = (const float*)d_in[6];
    const float* b1 = (const float*)d_in[7];
    const float* w2 = (const float*)d_in[8];
    const float* b2 = (const float*)d_in[9];
    const float* w3 = (const float*)d_in[10];
    const float* b3 = (const float*)d_in[11];

    char* ws = (char*)d_ws;
    unsigned short* Wb = (unsigned short*)(ws);                  // 8,388,608 B
    unsigned short* Xt = (unsigned short*)(ws + 8388608);        // 4,227,072 B
    unsigned short* Qp = (unsigned short*)(ws + 12615680);       // 8,388,608 B
    unsigned short* Kp = (unsigned short*)(ws + 21004288);       // 8,388,608 B
    // stats alias the Xt region (dead after conv):
    float* pstats = (float*)(ws + 8388608);                      // 1,048,576 B
    float* fstats = (float*)(ws + 8388608 + 1048576);            //   262,144 B

    float* out_ctx  = (float*)d_out;
    float* out_attn = out_ctx + 1048576;

    prep_w_kernel<<<dim3(16, 16), 256, 0, stream>>>(w0, w1, w2, w3, Wb);
    prep_x_kernel<<<dim3(16, 8, 4), 256, 0, stream>>>(Q, K, Xt);
    conv_pair_kernel<<<dim3(256), 256, 0, stream>>>(Xt, Wb, b0, b1, b2, b3, Qp, Kp);
    attn_stats_kernel<<<dim3(4, 16, 16), 256, 0, stream>>>(Qp, Kp, pstats);
    attn_combine_kernel<<<dim3(16, 16), 256, 0, stream>>>(pstats, fstats, out_ctx);
    attn_apply_kernel<<<dim3(4, 16, 16), 256, 0, stream>>>(Qp, Kp, V, fstats,
                                                           out_ctx, out_attn);
}

// Round 7
// 355.005 us; speedup vs baseline: 4.2957x; 1.0299x over previous
//
#include <hip/hip_runtime.h>
#include <math.h>

#define C_CH 512
#define L_SEQ 1024
#define DK 64
#define NP 4
#define SC2 0.1803368801111f   // 0.125 * log2(e)

typedef __attribute__((ext_vector_type(8))) short short8;
typedef __attribute__((ext_vector_type(4))) float f32x4;

__device__ __forceinline__ unsigned short f2bf(float f) {
    union { float f; unsigned u; } v; v.f = f;
    unsigned u = v.u;
    u += 0x7FFFu + ((u >> 16) & 1u);   // RNE
    return (unsigned short)(u >> 16);
}

__device__ __forceinline__ void unpack_tri(int t, int& qt, int& kt) {
    int q = (int)((sqrtf(8.f * t + 1.f) - 1.f) * 0.5f);
    while ((q + 1) * (q + 2) / 2 <= t) q++;
    while (q * (q + 1) / 2 > t) q--;
    qt = q;
    kt = t - q * (q + 1) / 2;
}

// ---------------------------------------------------------------------------
// Prep 1: Wb[tg][co][ci] = bf16(W[co][ci][t]),  tg = toff[plane]+t (16 slices)
// ---------------------------------------------------------------------------
__global__ __launch_bounds__(256)
void prep_w_kernel(const float* __restrict__ w0, const float* __restrict__ w1,
                   const float* __restrict__ w2, const float* __restrict__ w3,
                   unsigned short* __restrict__ Wb) {
    int tg = blockIdx.y;
    int plane, t;
    if (tg < 1)      { plane = 0; t = tg; }
    else if (tg < 4) { plane = 1; t = tg - 1; }
    else if (tg < 9) { plane = 2; t = tg - 4; }
    else             { plane = 3; t = tg - 9; }
    const float* W = (plane == 0) ? w0 : (plane == 1) ? w1 : (plane == 2) ? w2 : w3;
    const int f = (plane == 0) ? 1 : (plane == 1) ? 3 : (plane == 2) ? 5 : 7;

    int co = blockIdx.x * 32 + (threadIdx.x >> 3);
    int c8 = threadIdx.x & 7;
    for (int it = 0; it < 8; it++) {
        int ci = c8 * 8 + it * 64;
        unsigned short o[8];
#pragma unroll
        for (int j = 0; j < 8; j++)
            o[j] = f2bf(W[(size_t)(co * C_CH + ci + j) * f + t]);
        *(short8*)&Wb[((size_t)tg * C_CH + co) * C_CH + ci] = *(short8*)o;
    }
}

// ---------------------------------------------------------------------------
// Prep 2: Xt[tb][pos+4][ci] = bf16(X[tb][ci][pos]); rows 0..3 / 1028..1031 zero.
// ---------------------------------------------------------------------------
__global__ __launch_bounds__(256)
void prep_x_kernel(const float* __restrict__ Qin, const float* __restrict__ Kin,
                   unsigned short* __restrict__ Xt) {
    int tb = blockIdx.z;
    int tensor = tb >> 1, b = tb & 1;
    const float* X = (tensor ? Kin : Qin) + (size_t)b * C_CH * L_SEQ;
    unsigned short* O = Xt + (size_t)tb * 1032 * C_CH;

    int pos0 = blockIdx.x * 64;
    int ci0  = blockIdx.y * 64;
    int tid = threadIdx.x;

    __shared__ float tile[64][65];
    int tx = tid & 15, ty = tid >> 4;
#pragma unroll
    for (int rr = 0; rr < 4; rr++) {
        int ci_l = ty + rr * 16;
        float4 v = *(const float4*)&X[(size_t)(ci0 + ci_l) * L_SEQ + pos0 + tx * 4];
        tile[tx * 4 + 0][ci_l] = v.x;
        tile[tx * 4 + 1][ci_l] = v.y;
        tile[tx * 4 + 2][ci_l] = v.z;
        tile[tx * 4 + 3][ci_l] = v.w;
    }
    __syncthreads();
#pragma unroll
    for (int pp = 0; pp < 2; pp++) {
        int pos_l = (tid >> 3) + pp * 32;
        int cg = (tid & 7) * 8;
        unsigned short o[8];
#pragma unroll
        for (int j = 0; j < 8; j++) o[j] = f2bf(tile[pos_l][cg + j]);
        *(short8*)&O[(size_t)(pos0 + pos_l + 4) * C_CH + ci0 + cg] = *(short8*)o;
    }
    if (blockIdx.x == 0) {
        int r = tid >> 6, cc = tid & 63;
        O[(size_t)r * C_CH + ci0 + cc] = 0;
    }
    if (blockIdx.x == 15) {
        int r = tid >> 6, cc = tid & 63;
        O[(size_t)(1028 + r) * C_CH + ci0 + cc] = 0;
    }
}

// ---------------------------------------------------------------------------
// Conv bf16-MFMA GEMM. 512 blocks, ONE 128co x 128pos tile each, 2 blocks/CU.
// ID map: 0-127 f1, 128-255 f3, 256-383 f7, 384-511 f5 -> CU c gets
// {f1,f7} or {f3,f5} = uniform 128 k-iters. Ping-pong LDS, 1 sync/iter.
// ---------------------------------------------------------------------------
__global__ __launch_bounds__(256)
void conv_mfma_kernel(const unsigned short* __restrict__ Xt,
                      const unsigned short* __restrict__ Wb,
                      const float* __restrict__ b0, const float* __restrict__ b1,
                      const float* __restrict__ b2, const float* __restrict__ b3,
                      unsigned short* __restrict__ Qp, unsigned short* __restrict__ Kp) {
    const int fs[4]   = {1, 3, 5, 7};
    const int toff[4] = {0, 1, 4, 9};
    int id = blockIdx.x;
    int plane, rel;
    if (id < 128)      { plane = 0; rel = id; }
    else if (id < 256) { plane = 1; rel = id - 128; }
    else if (id < 384) { plane = 3; rel = id - 256; }
    else               { plane = 2; rel = id - 384; }
    int co0  = (rel & 3) * 128;
    int pos0 = ((rel >> 2) & 7) * 128;
    int tb   = rel >> 5;
    int tensor = tb >> 1, b = tb & 1;
    const int f   = fs[plane];
    const int pad = (f - 1) >> 1;
    const int n   = f * 16;
    const float* bias = (plane == 0) ? b0 : (plane == 1) ? b1 : (plane == 2) ? b2 : b3;
    unsigned short* Out = tensor ? Kp : Qp;
    const unsigned short* Xbase = Xt + (size_t)tb * 1032 * C_CH;

    __shared__ __align__(16) unsigned short As[2][4096];
    __shared__ __align__(16) unsigned short Bs[2][4096];

    int tid  = threadIdx.x;
    int w    = tid >> 6;
    int lane = tid & 63;
    int l15  = lane & 15;
    int quad = lane >> 4;
    int wm = (w & 1) * 64;
    int wn = (w >> 1) * 64;
    int rowL = tid >> 2;
    int cS   = tid & 3;

    int woff[2];
#pragma unroll
    for (int rep = 0; rep < 2; rep++) {
        int r = rowL + rep * 64;
        int line = r >> 1;
        int sl = (((r & 1) << 2) | cS) ^ (line & 7);
        woff[rep] = line * 64 + sl * 8;
    }
    int aoff[4], boff[4];
#pragma unroll
    for (int mi = 0; mi < 4; mi++) {
        int r = wm + mi * 16 + l15;
        int line = r >> 1;
        aoff[mi] = line * 64 + ((((r & 1) << 2) | quad) ^ (line & 7)) * 8;
        int r2 = wn + mi * 16 + l15;
        int line2 = r2 >> 1;
        boff[mi] = line2 * 64 + ((((r2 & 1) << 2) | quad) ^ (line2 & 7)) * 8;
    }

    f32x4 acc[4][4];
#pragma unroll
    for (int mi = 0; mi < 4; mi++)
#pragma unroll
        for (int ni = 0; ni < 4; ni++) acc[mi][ni] = (f32x4){0.f, 0.f, 0.f, 0.f};

    // prefetch iter 0
    short8 pA[2], pB[2];
    {
        const unsigned short* Wsl = Wb + ((size_t)toff[plane] * C_CH + co0) * C_CH;
        const unsigned short* Xsl = Xbase + (size_t)(pos0 - pad + 4) * C_CH;
#pragma unroll
        for (int rep = 0; rep < 2; rep++) {
            int r = rowL + rep * 64;
            pA[rep] = *(const short8*)&Wsl[(size_t)r * C_CH + cS * 8];
            pB[rep] = *(const short8*)&Xsl[(size_t)r * C_CH + cS * 8];
        }
    }

    for (int it = 0; it < n; it++) {
        int cur = it & 1;
        *(short8*)&As[cur][woff[0]] = pA[0];
        *(short8*)&As[cur][woff[1]] = pA[1];
        *(short8*)&Bs[cur][woff[0]] = pB[0];
        *(short8*)&Bs[cur][woff[1]] = pB[1];
        __syncthreads();

        if (it + 1 < n) {
            int t = (it + 1) >> 4, cc = (it + 1) & 15;
            const unsigned short* Wsl =
                Wb + ((size_t)(toff[plane] + t) * C_CH + co0) * C_CH + cc * 32;
            const unsigned short* Xsl =
                Xbase + (size_t)(pos0 + t - pad + 4) * C_CH + cc * 32;
#pragma unroll
            for (int rep = 0; rep < 2; rep++) {
                int r = rowL + rep * 64;
                pA[rep] = *(const short8*)&Wsl[(size_t)r * C_CH + cS * 8];
                pB[rep] = *(const short8*)&Xsl[(size_t)r * C_CH + cS * 8];
            }
        }

        short8 af[4], bf[4];
#pragma unroll
        for (int mi = 0; mi < 4; mi++) af[mi] = *(const short8*)&As[cur][aoff[mi]];
#pragma unroll
        for (int ni = 0; ni < 4; ni++) bf[ni] = *(const short8*)&Bs[cur][boff[ni]];
#pragma unroll
        for (int mi = 0; mi < 4; mi++)
#pragma unroll
            for (int ni = 0; ni < 4; ni++)
                acc[mi][ni] = __builtin_amdgcn_mfma_f32_16x16x32_bf16(
                    af[mi], bf[ni], acc[mi][ni], 0, 0, 0);
    }

    // epilogue: scatter to plane layout
#pragma unroll
    for (int mi = 0; mi < 4; mi++)
#pragma unroll
        for (int r = 0; r < 4; r++) {
            int co = co0 + wm + mi * 16 + quad * 4 + r;
            int h = co >> 6, cl = co & 63;
            float bv = bias[co];
            size_t sbase = (size_t)((b * 8 + h) * NP + plane) * L_SEQ * DK;
#pragma unroll
            for (int ni = 0; ni < 4; ni++) {
                int pos = pos0 + wn + ni * 16 + l15;
                int l = cl * 16 + (pos >> 6);
                int d = pos & 63;
                Out[sbase + (size_t)l * DK + d] = f2bf(acc[mi][ni][r] + bv);
            }
        }
}

// ---------------------------------------------------------------------------
// Stats: ONE 64x64 tile per block, flat triangular grid (136 x 16 bh).
// l_p[q] += sum_k exp2(s2); atomicAdd into zeroed lsum.
// ---------------------------------------------------------------------------
__global__ __launch_bounds__(256)
void attn_stats_kernel(const unsigned short* __restrict__ Qb,
                       const unsigned short* __restrict__ Kb,
                       float* __restrict__ lsum) {
    int qt, kt;
    unpack_tri(blockIdx.x, qt, kt);
    int bh = blockIdx.y;
    int tid = threadIdx.x;
    int q0 = qt * 64, k0 = kt * 64;
    bool diag = (kt == qt);

    int b2 = bh >> 3, h2 = bh & 7;
    int plane  = b2 * 2 + (h2 >> 2);
    int b_orig = (h2 >> 1) & 1;
    int h_base = (h2 & 1) * 4;
    int w = tid >> 6, lane = tid & 63, l15 = lane & 15, quad = lane >> 4;

    float l[NP][4];
#pragma unroll
    for (int p = 0; p < NP; p++)
        for (int r = 0; r < 4; r++) l[p][r] = 0.f;

#pragma unroll
    for (int p = 0; p < NP; p++) {
        size_t slice = (size_t)((b_orig * 8 + h_base + p) * NP + plane);
        const unsigned short* kb = Kb + slice * L_SEQ * DK;
        const unsigned short* qrow =
            Qb + (slice * L_SEQ + (size_t)(q0 + w * 16 + l15)) * DK + quad * 8;
        short8 qa0 = *(const short8*)(qrow);
        short8 qa1 = *(const short8*)(qrow + 32);

        f32x4 c[4];
#pragma unroll
        for (int s = 0; s < 4; s++) {
            const unsigned short* kr = kb + (size_t)(k0 + s * 16 + l15) * DK + quad * 8;
            short8 kb0 = *(const short8*)(kr);
            short8 kb1 = *(const short8*)(kr + 32);
            f32x4 acc = {0.f, 0.f, 0.f, 0.f};
            acc = __builtin_amdgcn_mfma_f32_16x16x32_bf16(qa0, kb0, acc, 0, 0, 0);
            acc = __builtin_amdgcn_mfma_f32_16x16x32_bf16(qa1, kb1, acc, 0, 0, 0);
            c[s] = acc;
        }
#pragma unroll
        for (int r = 0; r < 4; r++) {
            int row_local = quad * 4 + r + w * 16;
#pragma unroll
            for (int s = 0; s < 4; s++) {
                float x = c[s][r] * SC2;
                if (diag && (s * 16 + l15 > row_local)) x = -1e30f;
                l[p][r] += exp2f(x);
            }
        }
    }

    size_t base = (size_t)(bh * 16 + qt) * (NP * 64);
#pragma unroll
    for (int p = 0; p < NP; p++)
#pragma unroll
        for (int r = 0; r < 4; r++) {
            float ll = l[p][r];
            ll += __shfl_xor(ll, 1);
            ll += __shfl_xor(ll, 2);
            ll += __shfl_xor(ll, 4);
            ll += __shfl_xor(ll, 8);
            if (l15 == 0)
                unsafeAtomicAdd(&lsum[base + p * 64 + (w * 16 + quad * 4 + r)], ll);
        }
}

// ---------------------------------------------------------------------------
// Combine: z = log2(l); zero out_ctx tile; zero attn cols beyond diagonal.
// grid (16 qt, 16 bh).
// ---------------------------------------------------------------------------
__global__ __launch_bounds__(256)
void attn_combine_kernel(const float* __restrict__ lsum,
                         float* __restrict__ fstats,
                         float* __restrict__ out_ctx, float* __restrict__ out_attn) {
    int qt = blockIdx.x, bh = blockIdx.y;
    int tid = threadIdx.x;
    size_t sb = (size_t)(bh * 16 + qt) * (NP * 64);
    fstats[sb + tid] = __log2f(lsum[sb + tid]);

    int r = tid >> 2, c = (tid & 3) * 16;
    float4 z = make_float4(0.f, 0.f, 0.f, 0.f);
    size_t cbase = ((size_t)bh * L_SEQ + qt * 64 + r) * DK + c;
#pragma unroll
    for (int j = 0; j < 4; j++)
        *(float4*)&out_ctx[cbase + j * 4] = z;

    // zero-fill masked attn region for these 64 q-rows
    int kz = (qt + 1) * 64;
    size_t abase = ((size_t)bh * L_SEQ + qt * 64 + r) * L_SEQ;
    for (int k = kz + (tid & 3) * 4; k < L_SEQ; k += 16)
        *(float4*)&out_attn[abase + k] = z;
}

// ---------------------------------------------------------------------------
// Apply: ONE 64x64 tile per block, flat triangular grid (136 x 16 bh).
// attn = exp2(max_p(s2_p - z_p)); write attn; PV partial -> atomicAdd ctx.
// Single __syncthreads (vts); ast is wave-private.
// ---------------------------------------------------------------------------
__global__ __launch_bounds__(256)
void attn_apply_kernel(const unsigned short* __restrict__ Qb,
                       const unsigned short* __restrict__ Kb,
                       const float* __restrict__ V,
                       const float* __restrict__ fstats,
                       float* __restrict__ out_ctx, float* __restrict__ out_attn) {
    int qt, kt;
    unpack_tri(blockIdx.x, qt, kt);
    int bh = blockIdx.y;
    int tid = threadIdx.x;
    int q0 = qt * 64, k0 = kt * 64;
    bool diag = (kt == qt);

    int b2 = bh >> 3, h2 = bh & 7;
    int plane  = b2 * 2 + (h2 >> 2);
    int b_orig = (h2 >> 1) & 1;
    int h_base = (h2 & 1) * 4;
    int w = tid >> 6, lane = tid & 63, l15 = lane & 15, quad = lane >> 4;

    __shared__ float zsm[NP * 64];
    __shared__ __align__(16) unsigned short ast[64 * 80];
    __shared__ __align__(16) unsigned short vts[64 * 80];

    zsm[tid] = fstats[(size_t)(bh * 16 + qt) * (NP * 64) + tid];

    const unsigned short* kbase[NP];
    short8 qa[NP][2];
#pragma unroll
    for (int p = 0; p < NP; p++) {
        size_t slice = (size_t)((b_orig * 8 + h_base + p) * NP + plane);
        kbase[p] = Kb + slice * L_SEQ * DK;
        const unsigned short* qrow =
            Qb + (slice * L_SEQ + (size_t)(q0 + w * 16 + l15)) * DK + quad * 8;
        qa[p][0] = *(const short8*)(qrow);
        qa[p][1] = *(const short8*)(qrow + 32);
    }

    // stage V^T tile bf16
    {
        int kl = tid >> 2, db = (tid & 3) * 16;
        const float* vr = V + ((size_t)bh * L_SEQ + k0 + kl) * DK + db;
        float vv[16];
        *(float4*)&vv[0]  = *(const float4*)(vr);
        *(float4*)&vv[4]  = *(const float4*)(vr + 4);
        *(float4*)&vv[8]  = *(const float4*)(vr + 8);
        *(float4*)&vv[12] = *(const float4*)(vr + 12);
#pragma unroll
        for (int j = 0; j < 16; j++)
            vts[(db + j) * 80 + kl] = f2bf(vv[j]);
    }
    __syncthreads();   // zsm + vts ready

    // scores -> run = max_p (s2_p - z_p)
    float run[4][4];
#pragma unroll
    for (int s = 0; s < 4; s++)
        for (int r = 0; r < 4; r++) run[s][r] = -1e30f;

#pragma unroll
    for (int p = 0; p < NP; p++) {
        f32x4 c[4];
#pragma unroll
        for (int s = 0; s < 4; s++) {
            const unsigned short* kr =
                kbase[p] + (size_t)(k0 + s * 16 + l15) * DK + quad * 8;
            short8 kb0 = *(const short8*)(kr);
            short8 kb1 = *(const short8*)(kr + 32);
            f32x4 acc = {0.f, 0.f, 0.f, 0.f};
            acc = __builtin_amdgcn_mfma_f32_16x16x32_bf16(qa[p][0], kb0, acc, 0, 0, 0);
            acc = __builtin_amdgcn_mfma_f32_16x16x32_bf16(qa[p][1], kb1, acc, 0, 0, 0);
            c[s] = acc;
        }
#pragma unroll
        for (int r = 0; r < 4; r++) {
            float zp = zsm[p * 64 + (quad * 4 + r + w * 16)];
#pragma unroll
            for (int s = 0; s < 4; s++)
                run[s][r] = fmaxf(run[s][r], c[s][r] * SC2 - zp);
        }
    }

    // attn values: write + stash (ast rows are wave-private -> no barrier)
#pragma unroll
    for (int s = 0; s < 4; s++)
#pragma unroll
        for (int r = 0; r < 4; r++) {
            int qloc = w * 16 + quad * 4 + r;
            bool masked = diag && (s * 16 + l15 > qloc);
            float a = masked ? 0.f : exp2f(run[s][r]);
            out_attn[((size_t)bh * L_SEQ + q0 + qloc) * L_SEQ + k0 + s * 16 + l15] = a;
            ast[qloc * 80 + s * 16 + l15] = f2bf(a);
        }

    // PV partial
    f32x4 ctxc[4];
#pragma unroll
    for (int ds = 0; ds < 4; ds++) ctxc[ds] = (f32x4){0.f, 0.f, 0.f, 0.f};
    short8 af0 = *(const short8*)&ast[(w * 16 + l15) * 80 + quad * 8];
    short8 af1 = *(const short8*)&ast[(w * 16 + l15) * 80 + 32 + quad * 8];
#pragma unroll
    for (int ds = 0; ds < 4; ds++) {
        short8 bf0 = *(const short8*)&vts[(ds * 16 + l15) * 80 + quad * 8];
        short8 bf1 = *(const short8*)&vts[(ds * 16 + l15) * 80 + 32 + quad * 8];
        ctxc[ds] = __builtin_amdgcn_mfma_f32_16x16x32_bf16(af0, bf0, ctxc[ds], 0, 0, 0);
        ctxc[ds] = __builtin_amdgcn_mfma_f32_16x16x32_bf16(af1, bf1, ctxc[ds], 0, 0, 0);
    }

#pragma unroll
    for (int ds = 0; ds < 4; ds++)
#pragma unroll
        for (int r = 0; r < 4; r++) {
            int qg = q0 + w * 16 + quad * 4 + r;
            unsafeAtomicAdd(&out_ctx[((size_t)bh * L_SEQ + qg) * DK + ds * 16 + l15],
                            ctxc[ds][r]);
        }
}

// ---------------------------------------------------------------------------
extern "C" void kernel_launch(void* const* d_in, const int* in_sizes, int n_in,
                              void* d_out, int out_size, void* d_ws, size_t ws_size,
                              hipStream_t stream) {
    const float* Q  = (const float*)d_in[0];
    const float* K  = (const float*)d_in[1];
    const float* V  = (const float*)d_in[2];
    const float* w0 = (const float*)d_in[4];
    const float* b0 = (const float*)d_in[5];
    const float* w1 = (const float*)d_in[6];
    const float* b1 = (const float*)d_in[7];
    const float* w2 = (const float*)d_in[8];
    const float* b2 = (const float*)d_in[9];
    const float* w3 = (const float*)d_in[10];
    const float* b3 = (const float*)d_in[11];

    char* ws = (char*)d_ws;
    unsigned short* Wb = (unsigned short*)(ws);                  // 8,388,608 B
    unsigned short* Xt = (unsigned short*)(ws + 8388608);        // 4,227,072 B
    unsigned short* Qp = (unsigned short*)(ws + 12615680);       // 8,388,608 B
    unsigned short* Kp = (unsigned short*)(ws + 21004288);       // 8,388,608 B
    // stats alias the Xt region (dead after conv):
    float* lsum   = (float*)(ws + 8388608);                      // 262,144 B
    float* fstats = (float*)(ws + 8388608 + 262144);             // 262,144 B

    float* out_ctx  = (float*)d_out;
    float* out_attn = out_ctx + 1048576;

    prep_w_kernel<<<dim3(16, 16), 256, 0, stream>>>(w0, w1, w2, w3, Wb);
    prep_x_kernel<<<dim3(16, 8, 4), 256, 0, stream>>>(Q, K, Xt);
    conv_mfma_kernel<<<dim3(512), 256, 0, stream>>>(Xt, Wb, b0, b1, b2, b3, Qp, Kp);
    hipMemsetAsync(lsum, 0, 262144, stream);
    attn_stats_kernel<<<dim3(136, 16), 256, 0, stream>>>(Qp, Kp, lsum);
    attn_combine_kernel<<<dim3(16, 16), 256, 0, stream>>>(lsum, fstats, out_ctx, out_attn);
    attn_apply_kernel<<<dim3(136, 16), 256, 0, stream>>>(Qp, Kp, V, fstats,
                                                         out_ctx, out_attn);
}